// Round 3
// baseline (358.621 us; speedup 1.0000x reference)
//
#include <hip/hip_runtime.h>
#include <hip/hip_bf16.h>
#include <stdint.h>

typedef unsigned short u16;
typedef unsigned int u32;
typedef __bf16 bf16x8 __attribute__((ext_vector_type(8)));
typedef float f32x4 __attribute__((ext_vector_type(4)));

#define B_   2
#define S_   2048
#define D_   1024
#define H_   16
#define HD_  64

__device__ __forceinline__ u16 f2bf(float f) {
    u32 u = __float_as_uint(f);
    u32 r = (u + 0x7FFFu + ((u >> 16) & 1u)) >> 16;   // RNE; inputs never NaN/Inf
    return (u16)r;
}
__device__ __forceinline__ float bf2f(u16 s) { return __uint_as_float(((u32)s) << 16); }

__device__ __forceinline__ f32x4 mfma16(bf16x8 a, bf16x8 b, f32x4 c) {
    return __builtin_amdgcn_mfma_f32_16x16x32_bf16(a, b, c, 0, 0, 0);
}

// async global->LDS, 16B per lane; lds dest must be wave-uniform base (+lane*16)
__device__ __forceinline__ void gl16(const u16* g, u16* l) {
    __builtin_amdgcn_global_load_lds(
        (const __attribute__((address_space(1))) void*)g,
        (__attribute__((address_space(3))) void*)l, 16, 0, 0);
}

// ---------------------------------------------------------------------------
// Split fp32 -> (hi, lo) bf16 pair, elementwise (for x)
// ---------------------------------------------------------------------------
__global__ void split_x_kernel(const float* __restrict__ x,
                               u16* __restrict__ hi, u16* __restrict__ lo, int n4) {
    int i = blockIdx.x * blockDim.x + threadIdx.x;
    if (i >= n4) return;
    float4 v = reinterpret_cast<const float4*>(x)[i];
    u16 h0 = f2bf(v.x), h1 = f2bf(v.y), h2 = f2bf(v.z), h3 = f2bf(v.w);
    u16 l0 = f2bf(v.x - bf2f(h0)), l1 = f2bf(v.y - bf2f(h1));
    u16 l2 = f2bf(v.z - bf2f(h2)), l3 = f2bf(v.w - bf2f(h3));
    uint2 hp, lp;
    hp.x = (u32)h0 | ((u32)h1 << 16); hp.y = (u32)h2 | ((u32)h3 << 16);
    lp.x = (u32)l0 | ((u32)l1 << 16); lp.y = (u32)l2 | ((u32)l3 << 16);
    reinterpret_cast<uint2*>(hi)[i] = hp;
    reinterpret_cast<uint2*>(lo)[i] = lp;
}

// ---------------------------------------------------------------------------
// Split + transpose a [in=1024][out=1024] weight -> wT hi/lo [out][in]
// ---------------------------------------------------------------------------
__global__ void split_w_kernel(const float* __restrict__ w,
                               u16* __restrict__ thi, u16* __restrict__ tlo) {
    __shared__ float tile[32][33];
    int bi = blockIdx.y;   // input-dim block
    int bj = blockIdx.x;   // output-dim block
    int tx = threadIdx.x;  // 0..31
    int ty = threadIdx.y;  // 0..7
#pragma unroll
    for (int k = 0; k < 4; k++) {
        int r = ty + k * 8;
        tile[r][tx] = w[(size_t)(bi * 32 + r) * D_ + bj * 32 + tx];
    }
    __syncthreads();
#pragma unroll
    for (int k = 0; k < 4; k++) {
        int r = ty + k * 8;
        float v = tile[tx][r];
        u16 h = f2bf(v);
        u16 l = f2bf(v - bf2f(h));
        size_t idx = (size_t)(bj * 32 + r) * D_ + bi * 32 + tx;
        thi[idx] = h;
        tlo[idx] = l;
    }
}

// ---------------------------------------------------------------------------
// Split-bf16 GEMM: C = A @ B^T(stored row-major [N][K]) with hi/lo operands.
// MODE 0: fused QKV proj (+LIF).  N = 3072, per-128-col-tile proj select.
//         proj 0/1 (q/k) -> [bh][s][d];  proj 2 (v) -> [bh][d][s] transposed.
// MODE 3: o proj (+bias, fp32 out [4096][1024]).
// Tile BM x 128, BK=32, 4 waves (2x2, each (BM/2) x 64).
// Staging: global_load_lds w=16, linear LDS dest, SOURCE-swizzled chunks
// (chunk ^= (row>>1)&3) so frag ds_read_b128 hits all 8 bank-quads.
// XCD-aware bijective block swizzle (T1): grid%8==0 in both modes.
// ---------------------------------------------------------------------------
template <int MODE, int BM>
__global__ __launch_bounds__(256, 2)
void gemm_kernel(const u16* __restrict__ Ahg, const u16* __restrict__ Alg,
                 const u16* __restrict__ Bhg, const u16* __restrict__ Blg,
                 const float* __restrict__ b0, const float* __restrict__ b1,
                 const float* __restrict__ b2,
                 u16* __restrict__ o0, u16* __restrict__ o1, u16* __restrict__ o2,
                 float* __restrict__ o3) {
    constexpr int AMF = BM / 32;    // A frags per wave
    constexpr int APASS = BM / 64;  // 256-thread staging passes per A buffer
    constexpr int GX = (MODE == 0) ? 24 : 8;
    constexpr int GY = (MODE == 0) ? 32 : 64;
    __shared__ __align__(16) u16 lAh[BM * 32];
    __shared__ __align__(16) u16 lAl[BM * 32];
    __shared__ __align__(16) u16 lBh[128 * 32];
    __shared__ __align__(16) u16 lBl[128 * 32];

    const int t = threadIdx.x;
    // XCD swizzle: chunk the flat grid so 8 consecutive chunks -> 8 XCDs
    const int flat = blockIdx.y * GX + blockIdx.x;
    const int swz = (flat & 7) * ((GX * GY) / 8) + (flat >> 3);
    const int m0 = (swz / GX) * BM;
    const int n0 = (swz % GX) * 128;
    const int wid = t >> 6, lane = t & 63;
    const int wm = wid >> 1, wn = wid & 1;
    const int lr = lane & 15, lg = lane >> 4;

    f32x4 acc[AMF][4] = {};

    for (int kk = 0; kk < 32; ++kk) {
        const int k0 = kk * 32;
        // ---- stage tile kk (async DMA, linear dest, swizzled source) ----
#pragma unroll
        for (int p = 0; p < APASS; p++) {
            int idx = p * 256 + wid * 64 + lane;
            int row = idx >> 2, sl = idx & 3;
            int slx = sl ^ ((row >> 1) & 3);
            size_t ga = (size_t)(m0 + row) * D_ + k0 + slx * 8;
            u16* lbase = (u16*)(lAh + (size_t)(p * 256 + wid * 64) * 8);
            gl16(Ahg + ga, lbase);
            gl16(Alg + ga, lAl + (size_t)(p * 256 + wid * 64) * 8);
        }
#pragma unroll
        for (int p = 0; p < 2; p++) {
            int idx = p * 256 + wid * 64 + lane;
            int row = idx >> 2, sl = idx & 3;
            int slx = sl ^ ((row >> 1) & 3);
            size_t gb = (size_t)(n0 + row) * D_ + k0 + slx * 8;
            gl16(Bhg + gb, lBh + (size_t)(p * 256 + wid * 64) * 8);
            gl16(Blg + gb, lBl + (size_t)(p * 256 + wid * 64) * 8);
        }
        __syncthreads();  // compiler drains vmcnt(0) before barrier -> LDS valid

        bf16x8 ah[AMF], al[AMF], bh[4], bl[4];
#pragma unroll
        for (int m = 0; m < AMF; m++) {
            int row = wm * (BM / 2) + m * 16 + lr;
            int off = row * 32 + (lg ^ ((row >> 1) & 3)) * 8;
            ah[m] = *reinterpret_cast<const bf16x8*>(lAh + off);
            al[m] = *reinterpret_cast<const bf16x8*>(lAl + off);
        }
#pragma unroll
        for (int n = 0; n < 4; n++) {
            int row = wn * 64 + n * 16 + lr;
            int off = row * 32 + (lg ^ ((row >> 1) & 3)) * 8;
            bh[n] = *reinterpret_cast<const bf16x8*>(lBh + off);
            bl[n] = *reinterpret_cast<const bf16x8*>(lBl + off);
        }
#pragma unroll
        for (int m = 0; m < AMF; m++) {
#pragma unroll
            for (int n = 0; n < 4; n++) {
                acc[m][n] = mfma16(ah[m], bh[n], acc[m][n]);
                acc[m][n] = mfma16(ah[m], bl[n], acc[m][n]);
                acc[m][n] = mfma16(al[m], bh[n], acc[m][n]);
            }
        }
        __syncthreads();  // readers done before next stage overwrites
    }

    // ---- epilogue ----
    const int row0 = m0 + wm * (BM / 2);
    const int col0f = n0 + wn * 64;
    const int proj = col0f >> 10;  // 0..2 (MODE 0); 0 (MODE 3)
    const float* bias = (MODE == 3) ? b0 : (proj == 0 ? b0 : (proj == 1 ? b1 : b2));
    u16* dst = (proj == 0) ? o0 : (proj == 1) ? o1 : o2;
    const int colp0 = col0f & 1023;
#pragma unroll
    for (int m = 0; m < AMF; m++) {
#pragma unroll
        for (int n = 0; n < 4; n++) {
#pragma unroll
            for (int r = 0; r < 4; r++) {
                int row = row0 + m * 16 + lg * 4 + r;
                int colp = colp0 + n * 16 + lr;
                float cur = acc[m][n][r] + bias[colp];
                if (MODE == 0) {
                    // LIF: 4 steps, subtract reset (detached), spike after update
                    float mem = 0.f;
                    int cnt = 0;
#pragma unroll
                    for (int tt = 0; tt < 4; tt++) {
                        float reset = (mem > 1.f) ? 1.f : 0.f;
                        mem = 0.95f * mem;
                        mem = mem + cur;
                        mem = mem - reset;
                        cnt += (mem > 1.f) ? 1 : 0;
                    }
                    u16 agg = f2bf((float)cnt * 0.25f);
                    int b = row >> 11, s = row & 2047;
                    int h = colp >> 6, d = colp & 63;
                    size_t idx;
                    if (proj == 2)
                        idx = ((size_t)(b * H_ + h) * HD_ + d) * S_ + s;  // [bh][d][s]
                    else
                        idx = ((size_t)(b * H_ + h) * S_ + s) * HD_ + d;  // [bh][s][d]
                    dst[idx] = agg;
                } else {
                    o3[(size_t)row * D_ + colp] = cur;
                }
            }
        }
    }
}

// ---------------------------------------------------------------------------
// Attention, barrier-free. Grid (32 q-tiles of 64, 32 bh); 4 waves/block,
// each wave owns 16 q-rows independently. K/V frags read DIRECTLY from
// global (K/V per bh = 256KB each: L1 catches block-mate reuse, L2 holds
// the rest -- staging them in LDS was pure barrier overhead, cf m169).
// P transpose via wave-private swizzled LDS tile (same-wave DS ordering,
// no barrier). No __syncthreads anywhere.
// Scores in [0,8]; p = exp(s/8 - 4) -- no online max needed.
// Denominator via ones-operand MFMA on the SAME bf16 P (errors cancel).
// ---------------------------------------------------------------------------
__global__ __launch_bounds__(256, 4)
void attn_kernel(const u16* __restrict__ qa, const u16* __restrict__ ka,
                 const u16* __restrict__ vt,
                 u16* __restrict__ ohi, u16* __restrict__ olo) {
    __shared__ __align__(16) u16 Pt[4][16 * 64];  // 8KB, wave-private tiles

    const int t = threadIdx.x;
    const int wid = t >> 6, lane = t & 63;
    const int lr = lane & 15, lg = lane >> 4;

    // XCD swizzle: 128 consecutive flat ids (4 whole bh) per XCD chunk
    const int flat = blockIdx.y * 32 + blockIdx.x;
    const int swz = (flat & 7) * 128 + (flat >> 3);
    const int bh = swz / 32;
    const int q0 = (swz % 32) * 64 + wid * 16;  // this wave's q base

    const u16* qbase = qa + (size_t)bh * S_ * HD_;
    const u16* kbase = ka + (size_t)bh * S_ * HD_;
    const u16* vbase = vt + (size_t)bh * HD_ * S_;

    // Q fragments stay in registers for the whole K loop
    bf16x8 qf[2];
#pragma unroll
    for (int kc = 0; kc < 2; kc++)
        qf[kc] = *reinterpret_cast<const bf16x8*>(
            qbase + (size_t)(q0 + lr) * HD_ + kc * 32 + lg * 8);

    bf16x8 ones;
#pragma unroll
    for (int j = 0; j < 8; j++) ones[j] = (__bf16)1.0f;

    f32x4 oacc[4] = {};
    f32x4 ssum = {};
    u16* myP = &Pt[wid][0];

    for (int kt = 0; kt < 32; ++kt) {
        // S = Q K^T  (exact in bf16 MFMA: operands are multiples of 1/4)
        f32x4 sacc[4] = {};
        __builtin_amdgcn_s_setprio(1);
#pragma unroll
        for (int n = 0; n < 4; n++) {
#pragma unroll
            for (int kc = 0; kc < 2; kc++) {
                bf16x8 kb = *reinterpret_cast<const bf16x8*>(
                    kbase + (size_t)(kt * 64 + n * 16 + lr) * HD_ + kc * 32 + lg * 8);
                sacc[n] = mfma16(qf[kc], kb, sacc[n]);
            }
        }
        __builtin_amdgcn_s_setprio(0);
        // P = exp(s/8 - 4), write to wave-private swizzled LDS tile
#pragma unroll
        for (int n = 0; n < 4; n++)
#pragma unroll
            for (int r = 0; r < 4; r++) {
                float p = __expf(sacc[n][r] * 0.125f - 4.0f);
                int prow = lg * 4 + r;
                int pbyte = prow * 128 + (((n * 16 + lr) * 2) ^ ((prow & 7) << 4));
                *reinterpret_cast<u16*>(reinterpret_cast<char*>(myP) + pbyte) = f2bf(p);
            }
        // PV + row-sum (wave-private P: same-wave DS ordering suffices)
        bf16x8 pa[2];
#pragma unroll
        for (int kc = 0; kc < 2; kc++) {
            int sl = kc * 4 + lg;
            pa[kc] = *reinterpret_cast<const bf16x8*>(
                &myP[lr * 64 + ((sl ^ (lr & 7)) * 8)]);
        }
        __builtin_amdgcn_s_setprio(1);
#pragma unroll
        for (int n = 0; n < 4; n++) {
#pragma unroll
            for (int kc = 0; kc < 2; kc++) {
                bf16x8 vb = *reinterpret_cast<const bf16x8*>(
                    vbase + (size_t)(n * 16 + lr) * S_ + kt * 64 + (kc * 4 + lg) * 8);
                oacc[n] = mfma16(pa[kc], vb, oacc[n]);
            }
        }
        ssum = mfma16(pa[0], ones, ssum);
        ssum = mfma16(pa[1], ones, ssum);
        __builtin_amdgcn_s_setprio(0);
    }

    // epilogue: divide, split to hi/lo bf16 for the o-projection
    const int b = bh >> 4, h = bh & 15;
#pragma unroll
    for (int n = 0; n < 4; n++)
#pragma unroll
        for (int r = 0; r < 4; r++) {
            int q = q0 + lg * 4 + r;
            int d = n * 16 + lr;
            float v = oacc[n][r] / ssum[r];
            size_t gi = (size_t)(b * S_ + q) * D_ + h * 64 + d;
            u16 hi = f2bf(v);
            u16 lo = f2bf(v - bf2f(hi));
            ohi[gi] = hi;
            olo[gi] = lo;
        }
}

// ---------------------------------------------------------------------------
extern "C" void kernel_launch(void* const* d_in, const int* in_sizes, int n_in,
                              void* d_out, int out_size, void* d_ws, size_t ws_size,
                              hipStream_t stream) {
    (void)in_sizes; (void)n_in; (void)out_size; (void)ws_size;
    const float* x  = (const float*)d_in[0];
    const float* qw = (const float*)d_in[1];
    const float* qb = (const float*)d_in[2];
    const float* kw = (const float*)d_in[3];
    const float* kb = (const float*)d_in[4];
    const float* vw = (const float*)d_in[5];
    const float* vb = (const float*)d_in[6];
    const float* ow = (const float*)d_in[7];
    const float* ob = (const float*)d_in[8];

    u16* ws = (u16*)d_ws;
    const size_t C = 4194304;  // 4096*1024 elements
    u16* xhi = ws + 0 * C;
    u16* xlo = ws + 1 * C;
    u16* wth = ws + 2 * C;  // 4 transposed hi weights [out][in], 1M elems each (q,k,v,o)
    u16* wtl = ws + 3 * C;
    u16* qag = ws + 4 * C;
    u16* kag = ws + 5 * C;
    u16* vtg = ws + 6 * C;
    u16* ohi = ws + 7 * C;
    u16* olo = ws + 8 * C;

    split_x_kernel<<<4096, 256, 0, stream>>>(x, xhi, xlo, (int)(C / 4));
    const float* wsrc[4] = {qw, kw, vw, ow};
    for (int i = 0; i < 4; i++)
        split_w_kernel<<<dim3(32, 32), dim3(32, 8), 0, stream>>>(
            wsrc[i], wth + (size_t)i * 1048576, wtl + (size_t)i * 1048576);

    // fused QKV projection: A=[4096][1024] x B^T=[3072][1024], LIF epilogue
    gemm_kernel<0, 128><<<dim3(24, 32), 256, 0, stream>>>(
        xhi, xlo, wth, wtl, qb, kb, vb, qag, kag, vtg, nullptr);
    attn_kernel<<<dim3(32, 32), 256, 0, stream>>>(qag, kag, vtg, ohi, olo);
    // o-projection: BM=64 -> 512 blocks for 2 blocks/CU
    gemm_kernel<3, 64><<<dim3(8, 64), 256, 0, stream>>>(
        ohi, olo, wth + 3 * 1048576, wtl + 3 * 1048576, ob, nullptr, nullptr,
        nullptr, nullptr, nullptr, (float*)d_out);
}

// Round 4
// 187.762 us; speedup vs baseline: 1.9100x; 1.9100x over previous
//
#include <hip/hip_runtime.h>
#include <hip/hip_bf16.h>
#include <stdint.h>

typedef unsigned short u16;
typedef unsigned int u32;
typedef __bf16 bf16x8 __attribute__((ext_vector_type(8)));
typedef float f32x4 __attribute__((ext_vector_type(4)));

#define B_   2
#define S_   2048
#define D_   1024
#define H_   16
#define HD_  64

__device__ __forceinline__ u16 f2bf(float f) {
    u32 u = __float_as_uint(f);
    u32 r = (u + 0x7FFFu + ((u >> 16) & 1u)) >> 16;   // RNE; inputs never NaN/Inf
    return (u16)r;
}
__device__ __forceinline__ float bf2f(u16 s) { return __uint_as_float(((u32)s) << 16); }

__device__ __forceinline__ f32x4 mfma16(bf16x8 a, bf16x8 b, f32x4 c) {
    return __builtin_amdgcn_mfma_f32_16x16x32_bf16(a, b, c, 0, 0, 0);
}

// async global->LDS, 16B per lane; lds dest must be wave-uniform base (+lane*16)
__device__ __forceinline__ void gl16(const u16* g, u16* l) {
    __builtin_amdgcn_global_load_lds(
        (const __attribute__((address_space(1))) void*)g,
        (__attribute__((address_space(3))) void*)l, 16, 0, 0);
}

// ---------------------------------------------------------------------------
// Split fp32 -> (hi, lo) bf16 pair, elementwise (for x)
// ---------------------------------------------------------------------------
__global__ void split_x_kernel(const float* __restrict__ x,
                               u16* __restrict__ hi, u16* __restrict__ lo, int n4) {
    int i = blockIdx.x * blockDim.x + threadIdx.x;
    if (i >= n4) return;
    float4 v = reinterpret_cast<const float4*>(x)[i];
    u16 h0 = f2bf(v.x), h1 = f2bf(v.y), h2 = f2bf(v.z), h3 = f2bf(v.w);
    u16 l0 = f2bf(v.x - bf2f(h0)), l1 = f2bf(v.y - bf2f(h1));
    u16 l2 = f2bf(v.z - bf2f(h2)), l3 = f2bf(v.w - bf2f(h3));
    uint2 hp, lp;
    hp.x = (u32)h0 | ((u32)h1 << 16); hp.y = (u32)h2 | ((u32)h3 << 16);
    lp.x = (u32)l0 | ((u32)l1 << 16); lp.y = (u32)l2 | ((u32)l3 << 16);
    reinterpret_cast<uint2*>(hi)[i] = hp;
    reinterpret_cast<uint2*>(lo)[i] = lp;
}

// ---------------------------------------------------------------------------
// Split + transpose all 4 [in=1024][out=1024] weights -> wT hi/lo [out][in]
// (fused: blockIdx.z selects q/k/v/o weight)
// ---------------------------------------------------------------------------
__global__ void split_w_kernel(const float* __restrict__ qw, const float* __restrict__ kw,
                               const float* __restrict__ vw, const float* __restrict__ ow,
                               u16* __restrict__ thi_all, u16* __restrict__ tlo_all) {
    __shared__ float tile[32][33];
    const int z = blockIdx.z;
    const float* w = (z == 0) ? qw : (z == 1) ? kw : (z == 2) ? vw : ow;
    u16* thi = thi_all + (size_t)z * 1048576;
    u16* tlo = tlo_all + (size_t)z * 1048576;
    int bi = blockIdx.y;   // input-dim block
    int bj = blockIdx.x;   // output-dim block
    int tx = threadIdx.x;  // 0..31
    int ty = threadIdx.y;  // 0..7
#pragma unroll
    for (int k = 0; k < 4; k++) {
        int r = ty + k * 8;
        tile[r][tx] = w[(size_t)(bi * 32 + r) * D_ + bj * 32 + tx];
    }
    __syncthreads();
#pragma unroll
    for (int k = 0; k < 4; k++) {
        int r = ty + k * 8;
        float v = tile[tx][r];
        u16 h = f2bf(v);
        u16 l = f2bf(v - bf2f(h));
        size_t idx = (size_t)(bj * 32 + r) * D_ + bi * 32 + tx;
        thi[idx] = h;
        tlo[idx] = l;
    }
}

// ---------------------------------------------------------------------------
// Split-bf16 GEMM: C = A @ B^T(stored row-major [N][K]) with hi/lo operands.
// MODE 0: fused QKV proj (+LIF).  N = 3072, per-128-col-tile proj select.
//         proj 0/1 (q/k) -> [bh][s][d];  proj 2 (v) -> [bh][d][s] transposed.
// MODE 3: o proj (+bias, fp32 out [4096][1024]).
// Tile BM x 128, BK=32, 4 waves (2x2, each (BM/2) x 64).
// Staging: global_load_lds w=16, linear LDS dest, SOURCE-swizzled chunks
// (chunk ^= (row>>1)&3) so frag ds_read_b128 hits all 8 bank-quads.
// XCD-aware bijective block swizzle (T1): grid%8==0 in both modes.
// ---------------------------------------------------------------------------
template <int MODE, int BM>
__global__ __launch_bounds__(256, 2)
void gemm_kernel(const u16* __restrict__ Ahg, const u16* __restrict__ Alg,
                 const u16* __restrict__ Bhg, const u16* __restrict__ Blg,
                 const float* __restrict__ b0, const float* __restrict__ b1,
                 const float* __restrict__ b2,
                 u16* __restrict__ o0, u16* __restrict__ o1, u16* __restrict__ o2,
                 float* __restrict__ o3) {
    constexpr int AMF = BM / 32;    // A frags per wave
    constexpr int APASS = BM / 64;  // 256-thread staging passes per A buffer
    constexpr int GX = (MODE == 0) ? 24 : 8;
    constexpr int GY = (MODE == 0) ? 32 : 64;
    __shared__ __align__(16) u16 lAh[BM * 32];
    __shared__ __align__(16) u16 lAl[BM * 32];
    __shared__ __align__(16) u16 lBh[128 * 32];
    __shared__ __align__(16) u16 lBl[128 * 32];

    const int t = threadIdx.x;
    // XCD swizzle: chunk the flat grid so 8 consecutive chunks -> 8 XCDs
    const int flat = blockIdx.y * GX + blockIdx.x;
    const int swz = (flat & 7) * ((GX * GY) / 8) + (flat >> 3);
    const int m0 = (swz / GX) * BM;
    const int n0 = (swz % GX) * 128;
    const int wid = t >> 6, lane = t & 63;
    const int wm = wid >> 1, wn = wid & 1;
    const int lr = lane & 15, lg = lane >> 4;

    f32x4 acc[AMF][4] = {};

    for (int kk = 0; kk < 32; ++kk) {
        const int k0 = kk * 32;
        // ---- stage tile kk (async DMA, linear dest, swizzled source) ----
#pragma unroll
        for (int p = 0; p < APASS; p++) {
            int idx = p * 256 + wid * 64 + lane;
            int row = idx >> 2, sl = idx & 3;
            int slx = sl ^ ((row >> 1) & 3);
            size_t ga = (size_t)(m0 + row) * D_ + k0 + slx * 8;
            u16* lbase = (u16*)(lAh + (size_t)(p * 256 + wid * 64) * 8);
            gl16(Ahg + ga, lbase);
            gl16(Alg + ga, lAl + (size_t)(p * 256 + wid * 64) * 8);
        }
#pragma unroll
        for (int p = 0; p < 2; p++) {
            int idx = p * 256 + wid * 64 + lane;
            int row = idx >> 2, sl = idx & 3;
            int slx = sl ^ ((row >> 1) & 3);
            size_t gb = (size_t)(n0 + row) * D_ + k0 + slx * 8;
            gl16(Bhg + gb, lBh + (size_t)(p * 256 + wid * 64) * 8);
            gl16(Blg + gb, lBl + (size_t)(p * 256 + wid * 64) * 8);
        }
        __syncthreads();  // compiler drains vmcnt(0) before barrier -> LDS valid

        bf16x8 ah[AMF], al[AMF], bh[4], bl[4];
#pragma unroll
        for (int m = 0; m < AMF; m++) {
            int row = wm * (BM / 2) + m * 16 + lr;
            int off = row * 32 + (lg ^ ((row >> 1) & 3)) * 8;
            ah[m] = *reinterpret_cast<const bf16x8*>(lAh + off);
            al[m] = *reinterpret_cast<const bf16x8*>(lAl + off);
        }
#pragma unroll
        for (int n = 0; n < 4; n++) {
            int row = wn * 64 + n * 16 + lr;
            int off = row * 32 + (lg ^ ((row >> 1) & 3)) * 8;
            bh[n] = *reinterpret_cast<const bf16x8*>(lBh + off);
            bl[n] = *reinterpret_cast<const bf16x8*>(lBl + off);
        }
#pragma unroll
        for (int m = 0; m < AMF; m++) {
#pragma unroll
            for (int n = 0; n < 4; n++) {
                acc[m][n] = mfma16(ah[m], bh[n], acc[m][n]);
                acc[m][n] = mfma16(ah[m], bl[n], acc[m][n]);
                acc[m][n] = mfma16(al[m], bh[n], acc[m][n]);
            }
        }
        __syncthreads();  // readers done before next stage overwrites
    }

    // ---- epilogue ----
    const int row0 = m0 + wm * (BM / 2);
    const int col0f = n0 + wn * 64;
    const int proj = col0f >> 10;  // 0..2 (MODE 0); 0 (MODE 3)
    const float* bias = (MODE == 3) ? b0 : (proj == 0 ? b0 : (proj == 1 ? b1 : b2));
    u16* dst = (proj == 0) ? o0 : (proj == 1) ? o1 : o2;
    const int colp0 = col0f & 1023;
#pragma unroll
    for (int m = 0; m < AMF; m++) {
#pragma unroll
        for (int n = 0; n < 4; n++) {
#pragma unroll
            for (int r = 0; r < 4; r++) {
                int row = row0 + m * 16 + lg * 4 + r;
                int colp = colp0 + n * 16 + lr;
                float cur = acc[m][n][r] + bias[colp];
                if (MODE == 0) {
                    // LIF: 4 steps, subtract reset (detached), spike after update
                    float mem = 0.f;
                    int cnt = 0;
#pragma unroll
                    for (int tt = 0; tt < 4; tt++) {
                        float reset = (mem > 1.f) ? 1.f : 0.f;
                        mem = 0.95f * mem;
                        mem = mem + cur;
                        mem = mem - reset;
                        cnt += (mem > 1.f) ? 1 : 0;
                    }
                    u16 agg = f2bf((float)cnt * 0.25f);
                    int b = row >> 11, s = row & 2047;
                    int h = colp >> 6, d = colp & 63;
                    size_t idx;
                    if (proj == 2)
                        idx = ((size_t)(b * H_ + h) * HD_ + d) * S_ + s;  // [bh][d][s]
                    else
                        idx = ((size_t)(b * H_ + h) * S_ + s) * HD_ + d;  // [bh][s][d]
                    dst[idx] = agg;
                } else {
                    o3[(size_t)row * D_ + colp] = cur;
                }
            }
        }
    }
}

// ---------------------------------------------------------------------------
// Attention, T3-minimal 2-phase. Grid (16 q-tiles of 128, 32 bh); 4 waves,
// each wave owns 32 q-rows. K/V tiles (64 keys) double-buffered in LDS via
// global_load_lds (linear dest, source-XOR-swizzled per rule 21); per k-tile:
// STAGE(next) -> compute(cur) -> one __syncthreads (its vmcnt(0) drain is
// the DMA wait, hidden under compute).  P transpose via wave-private
// swizzled LDS tile (same-wave DS ordering, no barrier).
// Scores in [0,8]; p = exp(s/8 - 4) -- no online max needed.
// Denominator via ones-operand MFMA on the SAME bf16 P (errors cancel).
// LDS 48KB -> 3 blocks/CU.
// ---------------------------------------------------------------------------
__global__ __launch_bounds__(256, 3)
void attn_kernel(const u16* __restrict__ qa, const u16* __restrict__ ka,
                 const u16* __restrict__ vt,
                 u16* __restrict__ ohi, u16* __restrict__ olo) {
    __shared__ __align__(16) u16 Kb[2][64 * 64];   // 16 KB
    __shared__ __align__(16) u16 Vb[2][64 * 64];   // 16 KB
    __shared__ __align__(16) u16 Pt[4][32 * 64];   // 16 KB, wave-private tiles

    const int t = threadIdx.x;
    const int wid = t >> 6, lane = t & 63;
    const int lr = lane & 15, lg = lane >> 4;

    // XCD swizzle: 64 consecutive flat ids (4 whole bh) per XCD chunk
    const int flat = blockIdx.y * 16 + blockIdx.x;
    const int swz = (flat & 7) * 64 + (flat >> 3);
    const int bh = swz >> 4;
    const int q0 = (swz & 15) * 128;

    const u16* qbase = qa + (size_t)bh * S_ * HD_;
    const u16* kbase = ka + (size_t)bh * S_ * HD_;
    const u16* vbase = vt + (size_t)bh * HD_ * S_;

    // Q fragments stay in registers for the whole K loop
    bf16x8 qf[2][2];
#pragma unroll
    for (int m = 0; m < 2; m++)
#pragma unroll
        for (int kc = 0; kc < 2; kc++) {
            int row = q0 + wid * 32 + m * 16 + lr;
            qf[m][kc] = *reinterpret_cast<const bf16x8*>(
                qbase + (size_t)row * HD_ + kc * 32 + lg * 8);
        }

    bf16x8 ones;
#pragma unroll
    for (int j = 0; j < 8; j++) ones[j] = (__bf16)1.0f;

    f32x4 oacc[2][4] = {};
    f32x4 ssum[2] = {};
    u16* myP = &Pt[wid][0];

    // stage k-tile `kt` into buffer `buf`: 64 rows x 64 elems (8KB each of K,V)
    // linear LDS dest (wave-uniform base + lane*16), source chunk-XOR-swizzled
    auto STAGE = [&](int buf, int kt) {
#pragma unroll
        for (int p = 0; p < 2; p++) {
            int slot = p * 256 + wid * 64 + lane;
            int row = slot >> 3, sl = slot & 7;
            int slx = sl ^ (row & 7);
            u16* ldst = &Kb[buf][(size_t)(p * 256 + wid * 64) * 8];
            gl16(kbase + (size_t)(kt * 64 + row) * HD_ + slx * 8, ldst);
            gl16(vbase + (size_t)row * S_ + kt * 64 + slx * 8,
                 &Vb[buf][(size_t)(p * 256 + wid * 64) * 8]);
        }
    };

    STAGE(0, 0);
    __syncthreads();  // vmcnt(0) drain: buf0 ready
    int cur = 0;

    for (int kt = 0; kt < 32; ++kt) {
        if (kt < 31) STAGE(cur ^ 1, kt + 1);  // async DMA, waited at barrier below

        // S = Q K^T  (exact in bf16 MFMA: operands are multiples of 1/4)
        f32x4 sacc[2][4] = {};
        __builtin_amdgcn_s_setprio(1);
#pragma unroll
        for (int n = 0; n < 4; n++) {
            int row = n * 16 + lr;
#pragma unroll
            for (int kc = 0; kc < 2; kc++) {
                int sl = kc * 4 + lg;
                bf16x8 kb = *reinterpret_cast<const bf16x8*>(
                    &Kb[cur][row * 64 + ((sl ^ (row & 7)) * 8)]);
                sacc[0][n] = mfma16(qf[0][kc], kb, sacc[0][n]);
                sacc[1][n] = mfma16(qf[1][kc], kb, sacc[1][n]);
            }
        }
        __builtin_amdgcn_s_setprio(0);
        // P = exp(s/8 - 4), write to wave-private swizzled LDS tile
#pragma unroll
        for (int m = 0; m < 2; m++)
#pragma unroll
            for (int n = 0; n < 4; n++)
#pragma unroll
                for (int r = 0; r < 4; r++) {
                    float p = __expf(sacc[m][n][r] * 0.125f - 4.0f);
                    int prow = m * 16 + lg * 4 + r;
                    int pbyte = prow * 128 + (((n * 16 + lr) * 2) ^ ((prow & 7) << 4));
                    *reinterpret_cast<u16*>(reinterpret_cast<char*>(myP) + pbyte) = f2bf(p);
                }
        // PV + row-sum (wave-private P: same-wave DS ordering suffices)
        bf16x8 pa[2][2];
#pragma unroll
        for (int m = 0; m < 2; m++)
#pragma unroll
            for (int kc = 0; kc < 2; kc++) {
                int row = m * 16 + lr;
                int sl = kc * 4 + lg;
                pa[m][kc] = *reinterpret_cast<const bf16x8*>(
                    &myP[row * 64 + ((sl ^ (row & 7)) * 8)]);
            }
        __builtin_amdgcn_s_setprio(1);
#pragma unroll
        for (int n = 0; n < 4; n++) {
            int row = n * 16 + lr;  // row of V tile = d index
#pragma unroll
            for (int kc = 0; kc < 2; kc++) {
                int sl = kc * 4 + lg;
                bf16x8 vb = *reinterpret_cast<const bf16x8*>(
                    &Vb[cur][row * 64 + ((sl ^ (row & 7)) * 8)]);
                oacc[0][n] = mfma16(pa[0][kc], vb, oacc[0][n]);
                oacc[1][n] = mfma16(pa[1][kc], vb, oacc[1][n]);
            }
        }
        ssum[0] = mfma16(pa[0][0], ones, ssum[0]);
        ssum[0] = mfma16(pa[0][1], ones, ssum[0]);
        ssum[1] = mfma16(pa[1][0], ones, ssum[1]);
        ssum[1] = mfma16(pa[1][1], ones, ssum[1]);
        __builtin_amdgcn_s_setprio(0);

        __syncthreads();  // drains vmcnt(0): next buf ready; all waves done with cur
        cur ^= 1;
    }

    // epilogue: divide, split to hi/lo bf16 for the o-projection
    const int b = bh >> 4, h = bh & 15;
#pragma unroll
    for (int m = 0; m < 2; m++)
#pragma unroll
        for (int n = 0; n < 4; n++)
#pragma unroll
            for (int r = 0; r < 4; r++) {
                int q = q0 + wid * 32 + m * 16 + lg * 4 + r;
                int d = n * 16 + lr;
                float v = oacc[m][n][r] / ssum[m][r];
                size_t gi = (size_t)(b * S_ + q) * D_ + h * 64 + d;
                u16 hi = f2bf(v);
                u16 lo = f2bf(v - bf2f(hi));
                ohi[gi] = hi;
                olo[gi] = lo;
            }
}

// ---------------------------------------------------------------------------
extern "C" void kernel_launch(void* const* d_in, const int* in_sizes, int n_in,
                              void* d_out, int out_size, void* d_ws, size_t ws_size,
                              hipStream_t stream) {
    (void)in_sizes; (void)n_in; (void)out_size; (void)ws_size;
    const float* x  = (const float*)d_in[0];
    const float* qw = (const float*)d_in[1];
    const float* qb = (const float*)d_in[2];
    const float* kw = (const float*)d_in[3];
    const float* kb = (const float*)d_in[4];
    const float* vw = (const float*)d_in[5];
    const float* vb = (const float*)d_in[6];
    const float* ow = (const float*)d_in[7];
    const float* ob = (const float*)d_in[8];

    u16* ws = (u16*)d_ws;
    const size_t C = 4194304;  // 4096*1024 elements
    u16* xhi = ws + 0 * C;
    u16* xlo = ws + 1 * C;
    u16* wth = ws + 2 * C;  // 4 transposed hi weights [out][in], 1M elems each (q,k,v,o)
    u16* wtl = ws + 3 * C;
    u16* qag = ws + 4 * C;
    u16* kag = ws + 5 * C;
    u16* vtg = ws + 6 * C;
    u16* ohi = ws + 7 * C;
    u16* olo = ws + 8 * C;

    split_x_kernel<<<4096, 256, 0, stream>>>(x, xhi, xlo, (int)(C / 4));
    split_w_kernel<<<dim3(32, 32, 4), dim3(32, 8), 0, stream>>>(
        qw, kw, vw, ow, wth, wtl);

    // fused QKV projection: A=[4096][1024] x B^T=[3072][1024], LIF epilogue
    gemm_kernel<0, 128><<<dim3(24, 32), 256, 0, stream>>>(
        xhi, xlo, wth, wtl, qb, kb, vb, qag, kag, vtg, nullptr);
    attn_kernel<<<dim3(16, 32), 256, 0, stream>>>(qag, kag, vtg, ohi, olo);
    // o-projection: BM=64 -> 512 blocks for 2 blocks/CU
    gemm_kernel<3, 64><<<dim3(8, 64), 256, 0, stream>>>(
        ohi, olo, wth + 3 * 1048576, wtl + 3 * 1048576, ob, nullptr, nullptr,
        nullptr, nullptr, nullptr, (float*)d_out);
}

// Round 5
// 178.411 us; speedup vs baseline: 2.0101x; 1.0524x over previous
//
#include <hip/hip_runtime.h>
#include <hip/hip_bf16.h>
#include <stdint.h>

typedef unsigned short u16;
typedef unsigned int u32;
typedef __bf16 bf16x8 __attribute__((ext_vector_type(8)));
typedef float f32x4 __attribute__((ext_vector_type(4)));

#define B_   2
#define S_   2048
#define D_   1024
#define H_   16
#define HD_  64

__device__ __forceinline__ u16 f2bf(float f) {
    u32 u = __float_as_uint(f);
    u32 r = (u + 0x7FFFu + ((u >> 16) & 1u)) >> 16;   // RNE; inputs never NaN/Inf
    return (u16)r;
}
__device__ __forceinline__ float bf2f(u16 s) { return __uint_as_float(((u32)s) << 16); }

__device__ __forceinline__ f32x4 mfma16(bf16x8 a, bf16x8 b, f32x4 c) {
    return __builtin_amdgcn_mfma_f32_16x16x32_bf16(a, b, c, 0, 0, 0);
}

// async global->LDS, 16B per lane; lds dest must be wave-uniform base (+lane*16)
__device__ __forceinline__ void gl16(const u16* g, u16* l) {
    __builtin_amdgcn_global_load_lds(
        (const __attribute__((address_space(1))) void*)g,
        (__attribute__((address_space(3))) void*)l, 16, 0, 0);
}

// ---------------------------------------------------------------------------
// Split fp32 -> (hi, lo) bf16 pair, elementwise (for x)
// ---------------------------------------------------------------------------
__global__ void split_x_kernel(const float* __restrict__ x,
                               u16* __restrict__ hi, u16* __restrict__ lo, int n4) {
    int i = blockIdx.x * blockDim.x + threadIdx.x;
    if (i >= n4) return;
    float4 v = reinterpret_cast<const float4*>(x)[i];
    u16 h0 = f2bf(v.x), h1 = f2bf(v.y), h2 = f2bf(v.z), h3 = f2bf(v.w);
    u16 l0 = f2bf(v.x - bf2f(h0)), l1 = f2bf(v.y - bf2f(h1));
    u16 l2 = f2bf(v.z - bf2f(h2)), l3 = f2bf(v.w - bf2f(h3));
    uint2 hp, lp;
    hp.x = (u32)h0 | ((u32)h1 << 16); hp.y = (u32)h2 | ((u32)h3 << 16);
    lp.x = (u32)l0 | ((u32)l1 << 16); lp.y = (u32)l2 | ((u32)l3 << 16);
    reinterpret_cast<uint2*>(hi)[i] = hp;
    reinterpret_cast<uint2*>(lo)[i] = lp;
}

// ---------------------------------------------------------------------------
// Split + transpose all 4 [in=1024][out=1024] weights -> wT hi/lo [out][in]
// (fused: blockIdx.z selects q/k/v/o weight)
// ---------------------------------------------------------------------------
__global__ void split_w_kernel(const float* __restrict__ qw, const float* __restrict__ kw,
                               const float* __restrict__ vw, const float* __restrict__ ow,
                               u16* __restrict__ thi_all, u16* __restrict__ tlo_all) {
    __shared__ float tile[32][33];
    const int z = blockIdx.z;
    const float* w = (z == 0) ? qw : (z == 1) ? kw : (z == 2) ? vw : ow;
    u16* thi = thi_all + (size_t)z * 1048576;
    u16* tlo = tlo_all + (size_t)z * 1048576;
    int bi = blockIdx.y;   // input-dim block
    int bj = blockIdx.x;   // output-dim block
    int tx = threadIdx.x;  // 0..31
    int ty = threadIdx.y;  // 0..7
#pragma unroll
    for (int k = 0; k < 4; k++) {
        int r = ty + k * 8;
        tile[r][tx] = w[(size_t)(bi * 32 + r) * D_ + bj * 32 + tx];
    }
    __syncthreads();
#pragma unroll
    for (int k = 0; k < 4; k++) {
        int r = ty + k * 8;
        float v = tile[tx][r];
        u16 h = f2bf(v);
        u16 l = f2bf(v - bf2f(h));
        size_t idx = (size_t)(bj * 32 + r) * D_ + bi * 32 + tx;
        thi[idx] = h;
        tlo[idx] = l;
    }
}

// ---------------------------------------------------------------------------
// Fused QKV projection GEMM, split-bf16 (hi/lo), LIF epilogue.
// C = x @ W^T, W rows stored [out][in]; triple MFMA (hh + hl + lh).
// Tile 128x192, BK=32, dbuf 2-phase: STAGE(next) -> compute(cur) -> 1 barrier.
// 4 waves (2x2), wave tile 64x96 -> acc[4][6], 72 MFMA/wave/k-step.
// Grid 16x32 = 512 blocks = exactly 2 blocks/CU at 80KB LDS (no tail round).
// Source chunk-XOR swizzle (slx = sl ^ ((row>>1)&3)) -> conflict-free frags.
// proj 0/1 (q/k) -> [bh][s][d]; proj 2 (v) -> [bh][d][s] transposed.
// ---------------------------------------------------------------------------
__global__ __launch_bounds__(256, 2)
void qkv_gemm(const u16* __restrict__ Ahg, const u16* __restrict__ Alg,
              const u16* __restrict__ Bhg, const u16* __restrict__ Blg,
              const float* __restrict__ qb, const float* __restrict__ kb,
              const float* __restrict__ vb,
              u16* __restrict__ o0, u16* __restrict__ o1, u16* __restrict__ o2) {
    __shared__ __align__(16) u16 lAh[2][128 * 32];  // 16 KB
    __shared__ __align__(16) u16 lAl[2][128 * 32];  // 16 KB
    __shared__ __align__(16) u16 lBh[2][192 * 32];  // 24 KB
    __shared__ __align__(16) u16 lBl[2][192 * 32];  // 24 KB

    const int t = threadIdx.x;
    const int flat = blockIdx.y * 16 + blockIdx.x;
    const int swz = (flat & 7) * 64 + (flat >> 3);   // bijective, 8 XCD chunks
    const int m0 = (swz >> 4) * 128;
    const int n0 = (swz & 15) * 192;
    const int wid = t >> 6, lane = t & 63;
    const int wm = wid >> 1, wn = wid & 1;
    const int lr = lane & 15, lg = lane >> 4;

    f32x4 acc[4][6] = {};

    auto STAGE = [&](int buf, int kk) {
        const int k0 = kk * 32;
#pragma unroll
        for (int p = 0; p < 2; p++) {          // A: 128 rows x 4 slots = 512 slots
            int idx = p * 256 + wid * 64 + lane;
            int row = idx >> 2, sl = idx & 3;
            int slx = sl ^ ((row >> 1) & 3);
            size_t ga = (size_t)(m0 + row) * D_ + k0 + slx * 8;
            gl16(Ahg + ga, &lAh[buf][(p * 256 + wid * 64) * 8]);
            gl16(Alg + ga, &lAl[buf][(p * 256 + wid * 64) * 8]);
        }
#pragma unroll
        for (int p = 0; p < 3; p++) {          // B: 192 rows x 4 slots = 768 slots
            int idx = p * 256 + wid * 64 + lane;
            int row = idx >> 2, sl = idx & 3;
            int slx = sl ^ ((row >> 1) & 3);
            size_t gb = (size_t)(n0 + row) * D_ + k0 + slx * 8;
            gl16(Bhg + gb, &lBh[buf][(p * 256 + wid * 64) * 8]);
            gl16(Blg + gb, &lBl[buf][(p * 256 + wid * 64) * 8]);
        }
    };

    STAGE(0, 0);
    __syncthreads();  // vmcnt(0) drain: buf0 ready
    int cur = 0;

    for (int kk = 0; kk < 32; ++kk) {
        if (kk < 31) STAGE(cur ^ 1, kk + 1);  // async DMA, hidden under MFMAs

        bf16x8 ah[4], al[4], bh[6], bl[6];
#pragma unroll
        for (int m = 0; m < 4; m++) {
            int row = wm * 64 + m * 16 + lr;
            int off = row * 32 + (lg ^ ((row >> 1) & 3)) * 8;
            ah[m] = *reinterpret_cast<const bf16x8*>(&lAh[cur][off]);
            al[m] = *reinterpret_cast<const bf16x8*>(&lAl[cur][off]);
        }
#pragma unroll
        for (int n = 0; n < 6; n++) {
            int row = wn * 96 + n * 16 + lr;
            int off = row * 32 + (lg ^ ((row >> 1) & 3)) * 8;
            bh[n] = *reinterpret_cast<const bf16x8*>(&lBh[cur][off]);
            bl[n] = *reinterpret_cast<const bf16x8*>(&lBl[cur][off]);
        }
#pragma unroll
        for (int m = 0; m < 4; m++) {
#pragma unroll
            for (int n = 0; n < 6; n++) {
                acc[m][n] = mfma16(ah[m], bh[n], acc[m][n]);
                acc[m][n] = mfma16(ah[m], bl[n], acc[m][n]);
                acc[m][n] = mfma16(al[m], bh[n], acc[m][n]);
            }
        }
        __syncthreads();  // drains vmcnt(0): next buf ready; all waves done with cur
        cur ^= 1;
    }

    // ---- epilogue: bias + LIF + scatter ----
#pragma unroll
    for (int m = 0; m < 4; m++) {
#pragma unroll
        for (int n = 0; n < 6; n++) {
            // fragment's 16 columns share one proj (16 | 1024 boundaries)
            int cbase = n0 + wn * 96 + n * 16;
            int proj = cbase >> 10;
            const float* bp = (proj == 0) ? qb : (proj == 1) ? kb : vb;
            u16* dst = (proj == 0) ? o0 : (proj == 1) ? o1 : o2;
#pragma unroll
            for (int r = 0; r < 4; r++) {
                int row = m0 + wm * 64 + m * 16 + lg * 4 + r;
                int colp = (cbase + lr) & 1023;
                float cur_i = acc[m][n][r] + bp[colp];
                // LIF: 4 steps, subtract reset (detached), spike after update
                float mem = 0.f;
                int cnt = 0;
#pragma unroll
                for (int tt = 0; tt < 4; tt++) {
                    float reset = (mem > 1.f) ? 1.f : 0.f;
                    mem = 0.95f * mem;
                    mem = mem + cur_i;
                    mem = mem - reset;
                    cnt += (mem > 1.f) ? 1 : 0;
                }
                u16 agg = f2bf((float)cnt * 0.25f);
                int b = row >> 11, s = row & 2047;
                int h = colp >> 6, d = colp & 63;
                size_t idx;
                if (proj == 2)
                    idx = ((size_t)(b * H_ + h) * HD_ + d) * S_ + s;  // [bh][d][s]
                else
                    idx = ((size_t)(b * H_ + h) * S_ + s) * HD_ + d;  // [bh][s][d]
                dst[idx] = agg;
            }
        }
    }
}

// ---------------------------------------------------------------------------
// Output projection, PLAIN bf16 (downstream of all spike thresholds --
// rounding here passes linearly to output, ~1e-4; split not needed).
// C = a @ W^T + bias, fp32 out. Tile 64x128, BK=32, dbuf 2-phase.
// 4 waves (2x2), wave tile 32x64 -> acc[2][4], 8 MFMA/wave/k-step.
// ---------------------------------------------------------------------------
__global__ __launch_bounds__(256, 2)
void o_gemm(const u16* __restrict__ Ag, const u16* __restrict__ Bhg,
            const float* __restrict__ bias, float* __restrict__ out) {
    __shared__ __align__(16) u16 lA[2][64 * 32];    // 8 KB
    __shared__ __align__(16) u16 lB[2][128 * 32];   // 16 KB

    const int t = threadIdx.x;
    const int flat = blockIdx.y * 8 + blockIdx.x;
    const int swz = (flat & 7) * 64 + (flat >> 3);
    const int m0 = (swz >> 3) * 64;
    const int n0 = (swz & 7) * 128;
    const int wid = t >> 6, lane = t & 63;
    const int wm = wid >> 1, wn = wid & 1;
    const int lr = lane & 15, lg = lane >> 4;

    f32x4 acc[2][4] = {};

    auto STAGE = [&](int buf, int kk) {
        const int k0 = kk * 32;
        {                                      // A: 64 rows x 4 slots = 256 slots
            int idx = wid * 64 + lane;
            int row = idx >> 2, sl = idx & 3;
            int slx = sl ^ ((row >> 1) & 3);
            gl16(Ag + (size_t)(m0 + row) * D_ + k0 + slx * 8,
                 &lA[buf][(wid * 64) * 8]);
        }
#pragma unroll
        for (int p = 0; p < 2; p++) {          // B: 128 rows x 4 slots = 512 slots
            int idx = p * 256 + wid * 64 + lane;
            int row = idx >> 2, sl = idx & 3;
            int slx = sl ^ ((row >> 1) & 3);
            gl16(Bhg + (size_t)(n0 + row) * D_ + k0 + slx * 8,
                 &lB[buf][(p * 256 + wid * 64) * 8]);
        }
    };

    STAGE(0, 0);
    __syncthreads();
    int cur = 0;

    for (int kk = 0; kk < 32; ++kk) {
        if (kk < 31) STAGE(cur ^ 1, kk + 1);

        bf16x8 af[2], bf[4];
#pragma unroll
        for (int m = 0; m < 2; m++) {
            int row = wm * 32 + m * 16 + lr;
            af[m] = *reinterpret_cast<const bf16x8*>(
                &lA[cur][row * 32 + (lg ^ ((row >> 1) & 3)) * 8]);
        }
#pragma unroll
        for (int n = 0; n < 4; n++) {
            int row = wn * 64 + n * 16 + lr;
            bf[n] = *reinterpret_cast<const bf16x8*>(
                &lB[cur][row * 32 + (lg ^ ((row >> 1) & 3)) * 8]);
        }
#pragma unroll
        for (int m = 0; m < 2; m++)
#pragma unroll
            for (int n = 0; n < 4; n++)
                acc[m][n] = mfma16(af[m], bf[n], acc[m][n]);

        __syncthreads();
        cur ^= 1;
    }

#pragma unroll
    for (int m = 0; m < 2; m++)
#pragma unroll
        for (int n = 0; n < 4; n++)
#pragma unroll
            for (int r = 0; r < 4; r++) {
                int row = m0 + wm * 32 + m * 16 + lg * 4 + r;
                int col = n0 + wn * 64 + n * 16 + lr;
                out[(size_t)row * D_ + col] = acc[m][n][r] + bias[col];
            }
}

// ---------------------------------------------------------------------------
// Attention, 2-phase dbuf (unchanged structure from R4). Grid (16 q-tiles
// of 128, 32 bh); 4 waves, each owns 32 q-rows. K/V double-buffered via
// global_load_lds; one barrier per k-tile. Wave-private swizzled P tile.
// Scores in [0,8]; p = exp(s/8 - 4). Denominator via ones-MFMA on same P.
// Epilogue now writes single bf16 (o-proj is plain bf16).
// ---------------------------------------------------------------------------
__global__ __launch_bounds__(256, 3)
void attn_kernel(const u16* __restrict__ qa, const u16* __restrict__ ka,
                 const u16* __restrict__ vt, u16* __restrict__ oag) {
    __shared__ __align__(16) u16 Kb[2][64 * 64];   // 16 KB
    __shared__ __align__(16) u16 Vb[2][64 * 64];   // 16 KB
    __shared__ __align__(16) u16 Pt[4][32 * 64];   // 16 KB, wave-private tiles

    const int t = threadIdx.x;
    const int wid = t >> 6, lane = t & 63;
    const int lr = lane & 15, lg = lane >> 4;

    const int flat = blockIdx.y * 16 + blockIdx.x;
    const int swz = (flat & 7) * 64 + (flat >> 3);
    const int bh = swz >> 4;
    const int q0 = (swz & 15) * 128;

    const u16* qbase = qa + (size_t)bh * S_ * HD_;
    const u16* kbase = ka + (size_t)bh * S_ * HD_;
    const u16* vbase = vt + (size_t)bh * HD_ * S_;

    bf16x8 qf[2][2];
#pragma unroll
    for (int m = 0; m < 2; m++)
#pragma unroll
        for (int kc = 0; kc < 2; kc++) {
            int row = q0 + wid * 32 + m * 16 + lr;
            qf[m][kc] = *reinterpret_cast<const bf16x8*>(
                qbase + (size_t)row * HD_ + kc * 32 + lg * 8);
        }

    bf16x8 ones;
#pragma unroll
    for (int j = 0; j < 8; j++) ones[j] = (__bf16)1.0f;

    f32x4 oacc[2][4] = {};
    f32x4 ssum[2] = {};
    u16* myP = &Pt[wid][0];

    auto STAGE = [&](int buf, int kt) {
#pragma unroll
        for (int p = 0; p < 2; p++) {
            int slot = p * 256 + wid * 64 + lane;
            int row = slot >> 3, sl = slot & 7;
            int slx = sl ^ (row & 7);
            gl16(kbase + (size_t)(kt * 64 + row) * HD_ + slx * 8,
                 &Kb[buf][(p * 256 + wid * 64) * 8]);
            gl16(vbase + (size_t)row * S_ + kt * 64 + slx * 8,
                 &Vb[buf][(p * 256 + wid * 64) * 8]);
        }
    };

    STAGE(0, 0);
    __syncthreads();
    int cur = 0;

    for (int kt = 0; kt < 32; ++kt) {
        if (kt < 31) STAGE(cur ^ 1, kt + 1);

        f32x4 sacc[2][4] = {};
        __builtin_amdgcn_s_setprio(1);
#pragma unroll
        for (int n = 0; n < 4; n++) {
            int row = n * 16 + lr;
#pragma unroll
            for (int kc = 0; kc < 2; kc++) {
                int sl = kc * 4 + lg;
                bf16x8 kb = *reinterpret_cast<const bf16x8*>(
                    &Kb[cur][row * 64 + ((sl ^ (row & 7)) * 8)]);
                sacc[0][n] = mfma16(qf[0][kc], kb, sacc[0][n]);
                sacc[1][n] = mfma16(qf[1][kc], kb, sacc[1][n]);
            }
        }
        __builtin_amdgcn_s_setprio(0);
#pragma unroll
        for (int m = 0; m < 2; m++)
#pragma unroll
            for (int n = 0; n < 4; n++)
#pragma unroll
                for (int r = 0; r < 4; r++) {
                    float p = __expf(sacc[m][n][r] * 0.125f - 4.0f);
                    int prow = m * 16 + lg * 4 + r;
                    int pbyte = prow * 128 + (((n * 16 + lr) * 2) ^ ((prow & 7) << 4));
                    *reinterpret_cast<u16*>(reinterpret_cast<char*>(myP) + pbyte) = f2bf(p);
                }
        bf16x8 pa[2][2];
#pragma unroll
        for (int m = 0; m < 2; m++)
#pragma unroll
            for (int kc = 0; kc < 2; kc++) {
                int row = m * 16 + lr;
                int sl = kc * 4 + lg;
                pa[m][kc] = *reinterpret_cast<const bf16x8*>(
                    &myP[row * 64 + ((sl ^ (row & 7)) * 8)]);
            }
        __builtin_amdgcn_s_setprio(1);
#pragma unroll
        for (int n = 0; n < 4; n++) {
            int row = n * 16 + lr;  // row of V tile = d index
#pragma unroll
            for (int kc = 0; kc < 2; kc++) {
                int sl = kc * 4 + lg;
                bf16x8 vb = *reinterpret_cast<const bf16x8*>(
                    &Vb[cur][row * 64 + ((sl ^ (row & 7)) * 8)]);
                oacc[0][n] = mfma16(pa[0][kc], vb, oacc[0][n]);
                oacc[1][n] = mfma16(pa[1][kc], vb, oacc[1][n]);
            }
        }
        ssum[0] = mfma16(pa[0][0], ones, ssum[0]);
        ssum[0] = mfma16(pa[0][1], ones, ssum[0]);
        ssum[1] = mfma16(pa[1][0], ones, ssum[1]);
        ssum[1] = mfma16(pa[1][1], ones, ssum[1]);
        __builtin_amdgcn_s_setprio(0);

        __syncthreads();
        cur ^= 1;
    }

    // epilogue: divide, write bf16 [B,S,D]
    const int b = bh >> 4, h = bh & 15;
#pragma unroll
    for (int m = 0; m < 2; m++)
#pragma unroll
        for (int n = 0; n < 4; n++)
#pragma unroll
            for (int r = 0; r < 4; r++) {
                int q = q0 + wid * 32 + m * 16 + lg * 4 + r;
                int d = n * 16 + lr;
                float v = oacc[m][n][r] / ssum[m][r];
                oag[(size_t)(b * S_ + q) * D_ + h * 64 + d] = f2bf(v);
            }
}

// ---------------------------------------------------------------------------
extern "C" void kernel_launch(void* const* d_in, const int* in_sizes, int n_in,
                              void* d_out, int out_size, void* d_ws, size_t ws_size,
                              hipStream_t stream) {
    (void)in_sizes; (void)n_in; (void)out_size; (void)ws_size;
    const float* x  = (const float*)d_in[0];
    const float* qw = (const float*)d_in[1];
    const float* qb = (const float*)d_in[2];
    const float* kw = (const float*)d_in[3];
    const float* kb = (const float*)d_in[4];
    const float* vw = (const float*)d_in[5];
    const float* vb = (const float*)d_in[6];
    const float* ow = (const float*)d_in[7];
    const float* ob = (const float*)d_in[8];

    u16* ws = (u16*)d_ws;
    const size_t C = 4194304;  // 4096*1024 elements
    u16* xhi = ws + 0 * C;
    u16* xlo = ws + 1 * C;
    u16* wth = ws + 2 * C;  // 4 transposed hi weights [out][in], 1M elems each (q,k,v,o)
    u16* wtl = ws + 3 * C;
    u16* qag = ws + 4 * C;
    u16* kag = ws + 5 * C;
    u16* vtg = ws + 6 * C;
    u16* oag = ws + 7 * C;

    split_x_kernel<<<4096, 256, 0, stream>>>(x, xhi, xlo, (int)(C / 4));
    split_w_kernel<<<dim3(32, 32, 4), dim3(32, 8), 0, stream>>>(
        qw, kw, vw, ow, wth, wtl);

    // fused QKV projection: A=[4096][1024] x B^T=[3072][1024], LIF epilogue
    qkv_gemm<<<dim3(16, 32), 256, 0, stream>>>(
        xhi, xlo, wth, wtl, qb, kb, vb, qag, kag, vtg);
    attn_kernel<<<dim3(16, 32), 256, 0, stream>>>(qag, kag, vtg, oag);
    // o-projection: plain bf16, tile 64x128 -> 512 blocks
    o_gemm<<<dim3(8, 64), 256, 0, stream>>>(
        oag, wth + 3 * 1048576, ob, (float*)d_out);
}

// Round 6
// 134.586 us; speedup vs baseline: 2.6646x; 1.3256x over previous
//
#include <hip/hip_runtime.h>
#include <hip/hip_bf16.h>
#include <stdint.h>

typedef unsigned short u16;
typedef unsigned int u32;
typedef __bf16 bf16x8 __attribute__((ext_vector_type(8)));
typedef float f32x4 __attribute__((ext_vector_type(4)));

#define B_   2
#define S_   2048
#define D_   1024
#define H_   16
#define HD_  64

__device__ __forceinline__ u16 f2bf(float f) {
    u32 u = __float_as_uint(f);
    u32 r = (u + 0x7FFFu + ((u >> 16) & 1u)) >> 16;   // RNE; inputs never NaN/Inf
    return (u16)r;
}
__device__ __forceinline__ float bf2f(u16 s) { return __uint_as_float(((u32)s) << 16); }

__device__ __forceinline__ f32x4 mfma16(bf16x8 a, bf16x8 b, f32x4 c) {
    return __builtin_amdgcn_mfma_f32_16x16x32_bf16(a, b, c, 0, 0, 0);
}

// async global->LDS, 16B per lane; lds dest must be wave-uniform base (+lane*16)
__device__ __forceinline__ void gl16(const u16* g, u16* l) {
    __builtin_amdgcn_global_load_lds(
        (const __attribute__((address_space(1))) void*)g,
        (__attribute__((address_space(3))) void*)l, 16, 0, 0);
}

// ---------------------------------------------------------------------------
// Convert fp32 -> bf16, elementwise (for x). Plain bf16 is enough: spike-flip
// analysis (R6) shows cur error sigma ~9e-4 -> ~10k flips, each <1e-4 at the
// final output. The hi/lo split was 3x MFMA + 2x staging for nothing.
// ---------------------------------------------------------------------------
__global__ void convert_x_kernel(const float* __restrict__ x,
                                 u16* __restrict__ o, int n4) {
    int i = blockIdx.x * blockDim.x + threadIdx.x;
    if (i >= n4) return;
    float4 v = reinterpret_cast<const float4*>(x)[i];
    uint2 hp;
    hp.x = (u32)f2bf(v.x) | ((u32)f2bf(v.y) << 16);
    hp.y = (u32)f2bf(v.z) | ((u32)f2bf(v.w) << 16);
    reinterpret_cast<uint2*>(o)[i] = hp;
}

// ---------------------------------------------------------------------------
// Transpose + convert all 4 [in=1024][out=1024] fp32 weights -> bf16 [out][in]
// (blockIdx.z selects q/k/v/o weight)
// ---------------------------------------------------------------------------
__global__ void trans_w_kernel(const float* __restrict__ qw, const float* __restrict__ kw,
                               const float* __restrict__ vw, const float* __restrict__ ow,
                               u16* __restrict__ thi_all) {
    __shared__ float tile[32][33];
    const int z = blockIdx.z;
    const float* w = (z == 0) ? qw : (z == 1) ? kw : (z == 2) ? vw : ow;
    u16* thi = thi_all + (size_t)z * 1048576;
    int bi = blockIdx.y;   // input-dim block
    int bj = blockIdx.x;   // output-dim block
    int tx = threadIdx.x;  // 0..31
    int ty = threadIdx.y;  // 0..7
#pragma unroll
    for (int k = 0; k < 4; k++) {
        int r = ty + k * 8;
        tile[r][tx] = w[(size_t)(bi * 32 + r) * D_ + bj * 32 + tx];
    }
    __syncthreads();
#pragma unroll
    for (int k = 0; k < 4; k++) {
        int r = ty + k * 8;
        thi[(size_t)(bj * 32 + r) * D_ + bi * 32 + tx] = f2bf(tile[tx][r]);
    }
}

// ---------------------------------------------------------------------------
// Fused QKV projection GEMM, plain bf16, LIF epilogue.
// C = x @ W^T, W stored [out][in]. Tile 128x128, BK=32, dbuf 2-phase:
// STAGE(next) -> compute(cur) -> 1 barrier. 4 waves (2x2), wave tile 64x64,
// 16 MFMA/wave/k-step. Grid 24x32 = 768 blocks, 32KB LDS -> 3-4 blocks/CU.
// Source chunk-XOR swizzle (slx = sl ^ ((row>>1)&3)) -> conflict-free frags.
// proj 0/1 (q/k) -> [bh][s][d]; proj 2 (v) -> [bh][d][s] transposed.
// ---------------------------------------------------------------------------
__global__ __launch_bounds__(256, 3)
void qkv_gemm(const u16* __restrict__ Ag, const u16* __restrict__ Bg,
              const float* __restrict__ qb, const float* __restrict__ kb,
              const float* __restrict__ vb,
              u16* __restrict__ o0, u16* __restrict__ o1, u16* __restrict__ o2) {
    __shared__ __align__(16) u16 lA[2][128 * 32];  // 16 KB
    __shared__ __align__(16) u16 lB[2][128 * 32];  // 16 KB

    const int t = threadIdx.x;
    const int flat = blockIdx.y * 24 + blockIdx.x;
    const int swz = (flat & 7) * 96 + (flat >> 3);   // bijective, 8 XCD chunks
    const int m0 = (swz / 24) * 128;
    const int n0 = (swz % 24) * 128;
    const int wid = t >> 6, lane = t & 63;
    const int wm = wid >> 1, wn = wid & 1;
    const int lr = lane & 15, lg = lane >> 4;

    f32x4 acc[4][4] = {};

    auto STAGE = [&](int buf, int kk) {
        const int k0 = kk * 32;
#pragma unroll
        for (int p = 0; p < 2; p++) {          // A/B: 128 rows x 4 slots = 512 slots
            int idx = p * 256 + wid * 64 + lane;
            int row = idx >> 2, sl = idx & 3;
            int slx = sl ^ ((row >> 1) & 3);
            gl16(Ag + (size_t)(m0 + row) * D_ + k0 + slx * 8,
                 &lA[buf][(p * 256 + wid * 64) * 8]);
            gl16(Bg + (size_t)(n0 + row) * D_ + k0 + slx * 8,
                 &lB[buf][(p * 256 + wid * 64) * 8]);
        }
    };

    STAGE(0, 0);
    __syncthreads();  // vmcnt(0) drain: buf0 ready
    int cur = 0;

    for (int kk = 0; kk < 32; ++kk) {
        if (kk < 31) STAGE(cur ^ 1, kk + 1);  // async DMA, hidden under MFMAs

        bf16x8 af[4], bf[4];
#pragma unroll
        for (int m = 0; m < 4; m++) {
            int row = wm * 64 + m * 16 + lr;
            af[m] = *reinterpret_cast<const bf16x8*>(
                &lA[cur][row * 32 + (lg ^ ((row >> 1) & 3)) * 8]);
        }
#pragma unroll
        for (int n = 0; n < 4; n++) {
            int row = wn * 64 + n * 16 + lr;
            bf[n] = *reinterpret_cast<const bf16x8*>(
                &lB[cur][row * 32 + (lg ^ ((row >> 1) & 3)) * 8]);
        }
#pragma unroll
        for (int m = 0; m < 4; m++)
#pragma unroll
            for (int n = 0; n < 4; n++)
                acc[m][n] = mfma16(af[m], bf[n], acc[m][n]);

        __syncthreads();  // drains vmcnt(0): next buf ready; all waves done with cur
        cur ^= 1;
    }

    // ---- epilogue: bias + LIF + scatter ----
    const int col0f = n0 + wn * 64;
    const int proj = col0f >> 10;  // whole wave-tile shares one proj (64 | 1024)
    const float* bp = (proj == 0) ? qb : (proj == 1) ? kb : vb;
    u16* dst = (proj == 0) ? o0 : (proj == 1) ? o1 : o2;
#pragma unroll
    for (int m = 0; m < 4; m++) {
#pragma unroll
        for (int n = 0; n < 4; n++) {
#pragma unroll
            for (int r = 0; r < 4; r++) {
                int row = m0 + wm * 64 + m * 16 + lg * 4 + r;
                int colp = (col0f + n * 16 + lr) & 1023;
                float cur_i = acc[m][n][r] + bp[colp];
                // LIF: 4 steps, subtract reset (detached), spike after update
                float mem = 0.f;
                int cnt = 0;
#pragma unroll
                for (int tt = 0; tt < 4; tt++) {
                    float reset = (mem > 1.f) ? 1.f : 0.f;
                    mem = 0.95f * mem;
                    mem = mem + cur_i;
                    mem = mem - reset;
                    cnt += (mem > 1.f) ? 1 : 0;
                }
                u16 agg = f2bf((float)cnt * 0.25f);
                int b = row >> 11, s = row & 2047;
                int h = colp >> 6, d = colp & 63;
                size_t idx;
                if (proj == 2)
                    idx = ((size_t)(b * H_ + h) * HD_ + d) * S_ + s;  // [bh][d][s]
                else
                    idx = ((size_t)(b * H_ + h) * S_ + s) * HD_ + d;  // [bh][s][d]
                dst[idx] = agg;
            }
        }
    }
}

// ---------------------------------------------------------------------------
// Output projection, plain bf16 (downstream of all spike thresholds).
// C = a @ W^T + bias, fp32 out. Tile 64x128, BK=32, dbuf 2-phase.
// ---------------------------------------------------------------------------
__global__ __launch_bounds__(256, 2)
void o_gemm(const u16* __restrict__ Ag, const u16* __restrict__ Bhg,
            const float* __restrict__ bias, float* __restrict__ out) {
    __shared__ __align__(16) u16 lA[2][64 * 32];    // 8 KB
    __shared__ __align__(16) u16 lB[2][128 * 32];   // 16 KB

    const int t = threadIdx.x;
    const int flat = blockIdx.y * 8 + blockIdx.x;
    const int swz = (flat & 7) * 64 + (flat >> 3);
    const int m0 = (swz >> 3) * 64;
    const int n0 = (swz & 7) * 128;
    const int wid = t >> 6, lane = t & 63;
    const int wm = wid >> 1, wn = wid & 1;
    const int lr = lane & 15, lg = lane >> 4;

    f32x4 acc[2][4] = {};

    auto STAGE = [&](int buf, int kk) {
        const int k0 = kk * 32;
        {                                      // A: 64 rows x 4 slots = 256 slots
            int idx = wid * 64 + lane;
            int row = idx >> 2, sl = idx & 3;
            int slx = sl ^ ((row >> 1) & 3);
            gl16(Ag + (size_t)(m0 + row) * D_ + k0 + slx * 8,
                 &lA[buf][(wid * 64) * 8]);
        }
#pragma unroll
        for (int p = 0; p < 2; p++) {          // B: 128 rows x 4 slots = 512 slots
            int idx = p * 256 + wid * 64 + lane;
            int row = idx >> 2, sl = idx & 3;
            int slx = sl ^ ((row >> 1) & 3);
            gl16(Bhg + (size_t)(n0 + row) * D_ + k0 + slx * 8,
                 &lB[buf][(p * 256 + wid * 64) * 8]);
        }
    };

    STAGE(0, 0);
    __syncthreads();
    int cur = 0;

    for (int kk = 0; kk < 32; ++kk) {
        if (kk < 31) STAGE(cur ^ 1, kk + 1);

        bf16x8 af[2], bf[4];
#pragma unroll
        for (int m = 0; m < 2; m++) {
            int row = wm * 32 + m * 16 + lr;
            af[m] = *reinterpret_cast<const bf16x8*>(
                &lA[cur][row * 32 + (lg ^ ((row >> 1) & 3)) * 8]);
        }
#pragma unroll
        for (int n = 0; n < 4; n++) {
            int row = wn * 64 + n * 16 + lr;
            bf[n] = *reinterpret_cast<const bf16x8*>(
                &lB[cur][row * 32 + (lg ^ ((row >> 1) & 3)) * 8]);
        }
#pragma unroll
        for (int m = 0; m < 2; m++)
#pragma unroll
            for (int n = 0; n < 4; n++)
                acc[m][n] = mfma16(af[m], bf[n], acc[m][n]);

        __syncthreads();
        cur ^= 1;
    }

#pragma unroll
    for (int m = 0; m < 2; m++)
#pragma unroll
        for (int n = 0; n < 4; n++)
#pragma unroll
            for (int r = 0; r < 4; r++) {
                int row = m0 + wm * 32 + m * 16 + lg * 4 + r;
                int col = n0 + wn * 64 + n * 16 + lr;
                out[(size_t)row * D_ + col] = acc[m][n][r] + bias[col];
            }
}

// ---------------------------------------------------------------------------
// Attention, 2-phase dbuf (unchanged from R5). Grid (16 q-tiles of 128,
// 32 bh); 4 waves, each owns 32 q-rows. K/V double-buffered via
// global_load_lds; one barrier per k-tile. Wave-private swizzled P tile.
// Scores in [0,8]; p = exp(s/8 - 4). Denominator via ones-MFMA on same P.
// ---------------------------------------------------------------------------
__global__ __launch_bounds__(256, 3)
void attn_kernel(const u16* __restrict__ qa, const u16* __restrict__ ka,
                 const u16* __restrict__ vt, u16* __restrict__ oag) {
    __shared__ __align__(16) u16 Kb[2][64 * 64];   // 16 KB
    __shared__ __align__(16) u16 Vb[2][64 * 64];   // 16 KB
    __shared__ __align__(16) u16 Pt[4][32 * 64];   // 16 KB, wave-private tiles

    const int t = threadIdx.x;
    const int wid = t >> 6, lane = t & 63;
    const int lr = lane & 15, lg = lane >> 4;

    const int flat = blockIdx.y * 16 + blockIdx.x;
    const int swz = (flat & 7) * 64 + (flat >> 3);
    const int bh = swz >> 4;
    const int q0 = (swz & 15) * 128;

    const u16* qbase = qa + (size_t)bh * S_ * HD_;
    const u16* kbase = ka + (size_t)bh * S_ * HD_;
    const u16* vbase = vt + (size_t)bh * HD_ * S_;

    bf16x8 qf[2][2];
#pragma unroll
    for (int m = 0; m < 2; m++)
#pragma unroll
        for (int kc = 0; kc < 2; kc++) {
            int row = q0 + wid * 32 + m * 16 + lr;
            qf[m][kc] = *reinterpret_cast<const bf16x8*>(
                qbase + (size_t)row * HD_ + kc * 32 + lg * 8);
        }

    bf16x8 ones;
#pragma unroll
    for (int j = 0; j < 8; j++) ones[j] = (__bf16)1.0f;

    f32x4 oacc[2][4] = {};
    f32x4 ssum[2] = {};
    u16* myP = &Pt[wid][0];

    auto STAGE = [&](int buf, int kt) {
#pragma unroll
        for (int p = 0; p < 2; p++) {
            int slot = p * 256 + wid * 64 + lane;
            int row = slot >> 3, sl = slot & 7;
            int slx = sl ^ (row & 7);
            gl16(kbase + (size_t)(kt * 64 + row) * HD_ + slx * 8,
                 &Kb[buf][(p * 256 + wid * 64) * 8]);
            gl16(vbase + (size_t)row * S_ + kt * 64 + slx * 8,
                 &Vb[buf][(p * 256 + wid * 64) * 8]);
        }
    };

    STAGE(0, 0);
    __syncthreads();
    int cur = 0;

    for (int kt = 0; kt < 32; ++kt) {
        if (kt < 31) STAGE(cur ^ 1, kt + 1);

        f32x4 sacc[2][4] = {};
        __builtin_amdgcn_s_setprio(1);
#pragma unroll
        for (int n = 0; n < 4; n++) {
            int row = n * 16 + lr;
#pragma unroll
            for (int kc = 0; kc < 2; kc++) {
                int sl = kc * 4 + lg;
                bf16x8 kb = *reinterpret_cast<const bf16x8*>(
                    &Kb[cur][row * 64 + ((sl ^ (row & 7)) * 8)]);
                sacc[0][n] = mfma16(qf[0][kc], kb, sacc[0][n]);
                sacc[1][n] = mfma16(qf[1][kc], kb, sacc[1][n]);
            }
        }
        __builtin_amdgcn_s_setprio(0);
#pragma unroll
        for (int m = 0; m < 2; m++)
#pragma unroll
            for (int n = 0; n < 4; n++)
#pragma unroll
                for (int r = 0; r < 4; r++) {
                    float p = __expf(sacc[m][n][r] * 0.125f - 4.0f);
                    int prow = m * 16 + lg * 4 + r;
                    int pbyte = prow * 128 + (((n * 16 + lr) * 2) ^ ((prow & 7) << 4));
                    *reinterpret_cast<u16*>(reinterpret_cast<char*>(myP) + pbyte) = f2bf(p);
                }
        bf16x8 pa[2][2];
#pragma unroll
        for (int m = 0; m < 2; m++)
#pragma unroll
            for (int kc = 0; kc < 2; kc++) {
                int row = m * 16 + lr;
                int sl = kc * 4 + lg;
                pa[m][kc] = *reinterpret_cast<const bf16x8*>(
                    &myP[row * 64 + ((sl ^ (row & 7)) * 8)]);
            }
        __builtin_amdgcn_s_setprio(1);
#pragma unroll
        for (int n = 0; n < 4; n++) {
            int row = n * 16 + lr;  // row of V tile = d index
#pragma unroll
            for (int kc = 0; kc < 2; kc++) {
                int sl = kc * 4 + lg;
                bf16x8 vb = *reinterpret_cast<const bf16x8*>(
                    &Vb[cur][row * 64 + ((sl ^ (row & 7)) * 8)]);
                oacc[0][n] = mfma16(pa[0][kc], vb, oacc[0][n]);
                oacc[1][n] = mfma16(pa[1][kc], vb, oacc[1][n]);
            }
        }
        ssum[0] = mfma16(pa[0][0], ones, ssum[0]);
        ssum[0] = mfma16(pa[0][1], ones, ssum[0]);
        ssum[1] = mfma16(pa[1][0], ones, ssum[1]);
        ssum[1] = mfma16(pa[1][1], ones, ssum[1]);
        __builtin_amdgcn_s_setprio(0);

        __syncthreads();
        cur ^= 1;
    }

    // epilogue: divide, write bf16 [B,S,D]
    const int b = bh >> 4, h = bh & 15;
#pragma unroll
    for (int m = 0; m < 2; m++)
#pragma unroll
        for (int n = 0; n < 4; n++)
#pragma unroll
            for (int r = 0; r < 4; r++) {
                int q = q0 + wid * 32 + m * 16 + lg * 4 + r;
                int d = n * 16 + lr;
                float v = oacc[m][n][r] / ssum[m][r];
                oag[(size_t)(b * S_ + q) * D_ + h * 64 + d] = f2bf(v);
            }
}

// ---------------------------------------------------------------------------
extern "C" void kernel_launch(void* const* d_in, const int* in_sizes, int n_in,
                              void* d_out, int out_size, void* d_ws, size_t ws_size,
                              hipStream_t stream) {
    (void)in_sizes; (void)n_in; (void)out_size; (void)ws_size;
    const float* x  = (const float*)d_in[0];
    const float* qw = (const float*)d_in[1];
    const float* qb = (const float*)d_in[2];
    const float* kw = (const float*)d_in[3];
    const float* kb = (const float*)d_in[4];
    const float* vw = (const float*)d_in[5];
    const float* vb = (const float*)d_in[6];
    const float* ow = (const float*)d_in[7];
    const float* ob = (const float*)d_in[8];

    u16* ws = (u16*)d_ws;
    const size_t C = 4194304;  // 4096*1024 elements
    u16* xbf = ws + 0 * C;
    u16* wt  = ws + 1 * C;  // 4 transposed bf16 weights [out][in] (q,k,v,o)
    u16* qag = ws + 2 * C;
    u16* kag = ws + 3 * C;
    u16* vtg = ws + 4 * C;
    u16* oag = ws + 5 * C;

    convert_x_kernel<<<4096, 256, 0, stream>>>(x, xbf, (int)(C / 4));
    trans_w_kernel<<<dim3(32, 32, 4), dim3(32, 8), 0, stream>>>(
        qw, kw, vw, ow, wt);

    // fused QKV projection: A=[4096][1024] x B^T=[3072][1024], LIF epilogue
    qkv_gemm<<<dim3(24, 32), 256, 0, stream>>>(
        xbf, wt, qb, kb, vb, qag, kag, vtg);
    attn_kernel<<<dim3(16, 32), 256, 0, stream>>>(qag, kag, vtg, oag);
    // o-projection: plain bf16, tile 64x128 -> 512 blocks
    o_gemm<<<dim3(8, 64), 256, 0, stream>>>(
        oag, wt + 3 * 1048576, ob, (float*)d_out);
}

// Round 7
// 127.744 us; speedup vs baseline: 2.8073x; 1.0536x over previous
//
#include <hip/hip_runtime.h>
#include <hip/hip_bf16.h>
#include <stdint.h>

typedef unsigned short u16;
typedef unsigned int u32;
typedef __bf16 bf16x8 __attribute__((ext_vector_type(8)));
typedef float f32x4 __attribute__((ext_vector_type(4)));

#define B_   2
#define S_   2048
#define D_   1024
#define H_   16
#define HD_  64

__device__ __forceinline__ u16 f2bf(float f) {
    u32 u = __float_as_uint(f);
    u32 r = (u + 0x7FFFu + ((u >> 16) & 1u)) >> 16;   // RNE; inputs never NaN/Inf
    return (u16)r;
}
__device__ __forceinline__ float bf2f(u16 s) { return __uint_as_float(((u32)s) << 16); }

__device__ __forceinline__ f32x4 mfma16(bf16x8 a, bf16x8 b, f32x4 c) {
    return __builtin_amdgcn_mfma_f32_16x16x32_bf16(a, b, c, 0, 0, 0);
}

// async global->LDS, 16B per lane; lds dest must be wave-uniform base (+lane*16)
__device__ __forceinline__ void gl16(const u16* g, u16* l) {
    __builtin_amdgcn_global_load_lds(
        (const __attribute__((address_space(1))) void*)g,
        (__attribute__((address_space(3))) void*)l, 16, 0, 0);
}

// ---------------------------------------------------------------------------
// Convert fp32 -> bf16, elementwise (for x). Plain bf16 is enough: spike-flip
// analysis (R6) shows cur error sigma ~9e-4 -> ~10k flips, each <1e-4 at the
// final output (absmax was bit-identical with/without the hi/lo split).
// ---------------------------------------------------------------------------
__global__ void convert_x_kernel(const float* __restrict__ x,
                                 u16* __restrict__ o, int n4) {
    int i = blockIdx.x * blockDim.x + threadIdx.x;
    if (i >= n4) return;
    float4 v = reinterpret_cast<const float4*>(x)[i];
    uint2 hp;
    hp.x = (u32)f2bf(v.x) | ((u32)f2bf(v.y) << 16);
    hp.y = (u32)f2bf(v.z) | ((u32)f2bf(v.w) << 16);
    reinterpret_cast<uint2*>(o)[i] = hp;
}

// ---------------------------------------------------------------------------
// Transpose + convert all 4 [in=1024][out=1024] fp32 weights -> bf16 [out][in]
// (blockIdx.z selects q/k/v/o weight)
// ---------------------------------------------------------------------------
__global__ void trans_w_kernel(const float* __restrict__ qw, const float* __restrict__ kw,
                               const float* __restrict__ vw, const float* __restrict__ ow,
                               u16* __restrict__ thi_all) {
    __shared__ float tile[32][33];
    const int z = blockIdx.z;
    const float* w = (z == 0) ? qw : (z == 1) ? kw : (z == 2) ? vw : ow;
    u16* thi = thi_all + (size_t)z * 1048576;
    int bi = blockIdx.y;   // input-dim block
    int bj = blockIdx.x;   // output-dim block
    int tx = threadIdx.x;  // 0..31
    int ty = threadIdx.y;  // 0..7
#pragma unroll
    for (int k = 0; k < 4; k++) {
        int r = ty + k * 8;
        tile[r][tx] = w[(size_t)(bi * 32 + r) * D_ + bj * 32 + tx];
    }
    __syncthreads();
#pragma unroll
    for (int k = 0; k < 4; k++) {
        int r = ty + k * 8;
        thi[(size_t)(bj * 32 + r) * D_ + bi * 32 + tx] = f2bf(tile[tx][r]);
    }
}

// ---------------------------------------------------------------------------
// Fused QKV projection GEMM, plain bf16, LIF epilogue.
// C = x @ W^T, W stored [out][in]. Tile 128x128, BK=32, dbuf 2-phase:
// STAGE(next) -> compute(cur) -> 1 barrier. 4 waves (2x2), wave tile 64x64,
// 16 MFMA/wave/k-step. Grid 24x32 = 768 blocks, 32KB LDS -> 3 blocks/CU.
// Source chunk-XOR swizzle (slx = sl ^ ((row>>1)&3)) -> conflict-free frags.
// proj 0/1 (q/k) -> [bh][s][d]; proj 2 (v) -> [bh][d][s] transposed.
// ---------------------------------------------------------------------------
__global__ __launch_bounds__(256, 3)
void qkv_gemm(const u16* __restrict__ Ag, const u16* __restrict__ Bg,
              const float* __restrict__ qb, const float* __restrict__ kb,
              const float* __restrict__ vb,
              u16* __restrict__ o0, u16* __restrict__ o1, u16* __restrict__ o2) {
    __shared__ __align__(16) u16 lA[2][128 * 32];  // 16 KB
    __shared__ __align__(16) u16 lB[2][128 * 32];  // 16 KB

    const int t = threadIdx.x;
    const int flat = blockIdx.y * 24 + blockIdx.x;
    const int swz = (flat & 7) * 96 + (flat >> 3);   // bijective, 8 XCD chunks
    const int m0 = (swz / 24) * 128;
    const int n0 = (swz % 24) * 128;
    const int wid = t >> 6, lane = t & 63;
    const int wm = wid >> 1, wn = wid & 1;
    const int lr = lane & 15, lg = lane >> 4;

    f32x4 acc[4][4] = {};

    auto STAGE = [&](int buf, int kk) {
        const int k0 = kk * 32;
#pragma unroll
        for (int p = 0; p < 2; p++) {          // A/B: 128 rows x 4 slots = 512 slots
            int idx = p * 256 + wid * 64 + lane;
            int row = idx >> 2, sl = idx & 3;
            int slx = sl ^ ((row >> 1) & 3);
            gl16(Ag + (size_t)(m0 + row) * D_ + k0 + slx * 8,
                 &lA[buf][(p * 256 + wid * 64) * 8]);
            gl16(Bg + (size_t)(n0 + row) * D_ + k0 + slx * 8,
                 &lB[buf][(p * 256 + wid * 64) * 8]);
        }
    };

    STAGE(0, 0);
    __syncthreads();  // vmcnt(0) drain: buf0 ready
    int cur = 0;

    for (int kk = 0; kk < 32; ++kk) {
        if (kk < 31) STAGE(cur ^ 1, kk + 1);  // async DMA, hidden under MFMAs

        bf16x8 af[4], bf[4];
#pragma unroll
        for (int m = 0; m < 4; m++) {
            int row = wm * 64 + m * 16 + lr;
            af[m] = *reinterpret_cast<const bf16x8*>(
                &lA[cur][row * 32 + (lg ^ ((row >> 1) & 3)) * 8]);
        }
#pragma unroll
        for (int n = 0; n < 4; n++) {
            int row = wn * 64 + n * 16 + lr;
            bf[n] = *reinterpret_cast<const bf16x8*>(
                &lB[cur][row * 32 + (lg ^ ((row >> 1) & 3)) * 8]);
        }
#pragma unroll
        for (int m = 0; m < 4; m++)
#pragma unroll
            for (int n = 0; n < 4; n++)
                acc[m][n] = mfma16(af[m], bf[n], acc[m][n]);

        __syncthreads();  // drains vmcnt(0): next buf ready; all waves done with cur
        cur ^= 1;
    }

    // ---- epilogue: bias + LIF + scatter ----
    const int col0f = n0 + wn * 64;
    const int proj = col0f >> 10;  // whole wave-tile shares one proj (64 | 1024)
    const float* bp = (proj == 0) ? qb : (proj == 1) ? kb : vb;
    u16* dst = (proj == 0) ? o0 : (proj == 1) ? o1 : o2;
#pragma unroll
    for (int m = 0; m < 4; m++) {
#pragma unroll
        for (int n = 0; n < 4; n++) {
#pragma unroll
            for (int r = 0; r < 4; r++) {
                int row = m0 + wm * 64 + m * 16 + lg * 4 + r;
                int colp = (col0f + n * 16 + lr) & 1023;
                float cur_i = acc[m][n][r] + bp[colp];
                // LIF: 4 steps, subtract reset (detached), spike after update
                float mem = 0.f;
                int cnt = 0;
#pragma unroll
                for (int tt = 0; tt < 4; tt++) {
                    float reset = (mem > 1.f) ? 1.f : 0.f;
                    mem = 0.95f * mem;
                    mem = mem + cur_i;
                    mem = mem - reset;
                    cnt += (mem > 1.f) ? 1 : 0;
                }
                // cnt*0.25 is exactly representable in bf16: truncate, no RNE
                u16 agg = (u16)(__float_as_uint((float)cnt * 0.25f) >> 16);
                int b = row >> 11, s = row & 2047;
                int h = colp >> 6, d = colp & 63;
                size_t idx;
                if (proj == 2)
                    idx = ((size_t)(b * H_ + h) * HD_ + d) * S_ + s;  // [bh][d][s]
                else
                    idx = ((size_t)(b * H_ + h) * S_ + s) * HD_ + d;  // [bh][s][d]
                dst[idx] = agg;
            }
        }
    }
}

// ---------------------------------------------------------------------------
// Output projection, plain bf16 (downstream of all spike thresholds).
// C = a @ W^T + bias, fp32 out. Tile 64x64, BK=32, dbuf 2-phase.
// Grid 16x64 = 1024 blocks = 4 blocks/CU (was 2/CU at 64x128 -- grid-limited).
// ---------------------------------------------------------------------------
__global__ __launch_bounds__(256, 4)
void o_gemm(const u16* __restrict__ Ag, const u16* __restrict__ Bhg,
            const float* __restrict__ bias, float* __restrict__ out) {
    __shared__ __align__(16) u16 lA[2][64 * 32];    // 8 KB
    __shared__ __align__(16) u16 lB[2][64 * 32];    // 8 KB

    const int t = threadIdx.x;
    const int flat = blockIdx.y * 16 + blockIdx.x;
    const int swz = (flat & 7) * 128 + (flat >> 3);  // 1024 blocks, bijective
    const int m0 = (swz >> 4) * 64;
    const int n0 = (swz & 15) * 64;
    const int wid = t >> 6, lane = t & 63;
    const int wm = wid >> 1, wn = wid & 1;
    const int lr = lane & 15, lg = lane >> 4;

    f32x4 acc[2][2] = {};

    auto STAGE = [&](int buf, int kk) {
        const int k0 = kk * 32;
        int idx = wid * 64 + lane;             // 256 slots = 64 rows x 4
        int row = idx >> 2, sl = idx & 3;
        int slx = sl ^ ((row >> 1) & 3);
        gl16(Ag + (size_t)(m0 + row) * D_ + k0 + slx * 8,
             &lA[buf][(wid * 64) * 8]);
        gl16(Bhg + (size_t)(n0 + row) * D_ + k0 + slx * 8,
             &lB[buf][(wid * 64) * 8]);
    };

    STAGE(0, 0);
    __syncthreads();
    int cur = 0;

    for (int kk = 0; kk < 32; ++kk) {
        if (kk < 31) STAGE(cur ^ 1, kk + 1);

        bf16x8 af[2], bf[2];
#pragma unroll
        for (int m = 0; m < 2; m++) {
            int row = wm * 32 + m * 16 + lr;
            af[m] = *reinterpret_cast<const bf16x8*>(
                &lA[cur][row * 32 + (lg ^ ((row >> 1) & 3)) * 8]);
        }
#pragma unroll
        for (int n = 0; n < 2; n++) {
            int row = wn * 32 + n * 16 + lr;
            bf[n] = *reinterpret_cast<const bf16x8*>(
                &lB[cur][row * 32 + (lg ^ ((row >> 1) & 3)) * 8]);
        }
#pragma unroll
        for (int m = 0; m < 2; m++)
#pragma unroll
            for (int n = 0; n < 2; n++)
                acc[m][n] = mfma16(af[m], bf[n], acc[m][n]);

        __syncthreads();
        cur ^= 1;
    }

#pragma unroll
    for (int m = 0; m < 2; m++)
#pragma unroll
        for (int n = 0; n < 2; n++)
#pragma unroll
            for (int r = 0; r < 4; r++) {
                int row = m0 + wm * 32 + m * 16 + lg * 4 + r;
                int col = n0 + wn * 32 + n * 16 + lr;
                out[(size_t)row * D_ + col] = acc[m][n][r] + bias[col];
            }
}

// ---------------------------------------------------------------------------
// Attention, 2-phase dbuf (structure unchanged from R6). Grid (16 q-tiles of
// 128, 32 bh); 4 waves, each owns 32 q-rows. K/V double-buffered via
// global_load_lds; one barrier per k-tile. Wave-private swizzled P tile.
// Scores in [0,8]; p = exp2(s*log2e/8 - 4*log2e)  [== exp(s/8-4)].
// Softmax pack: v_exp_f32 + v_cvt_pk_bf16_f32 pairs (rows r,r+1 share a
// packed dword; write lo b16 + hi>>16 b16) -- cuts ~100 VALU inst/tile/wave
// vs scalar f2bf. Denominator via ones-MFMA on the SAME bf16 P.
// ---------------------------------------------------------------------------
__global__ __launch_bounds__(256, 3)
void attn_kernel(const u16* __restrict__ qa, const u16* __restrict__ ka,
                 const u16* __restrict__ vt, u16* __restrict__ oag) {
    __shared__ __align__(16) u16 Kb[2][64 * 64];   // 16 KB
    __shared__ __align__(16) u16 Vb[2][64 * 64];   // 16 KB
    __shared__ __align__(16) u16 Pt[4][32 * 64];   // 16 KB, wave-private tiles

    const int t = threadIdx.x;
    const int wid = t >> 6, lane = t & 63;
    const int lr = lane & 15, lg = lane >> 4;

    const int flat = blockIdx.y * 16 + blockIdx.x;
    const int swz = (flat & 7) * 64 + (flat >> 3);
    const int bh = swz >> 4;
    const int q0 = (swz & 15) * 128;

    const u16* qbase = qa + (size_t)bh * S_ * HD_;
    const u16* kbase = ka + (size_t)bh * S_ * HD_;
    const u16* vbase = vt + (size_t)bh * HD_ * S_;

    bf16x8 qf[2][2];
#pragma unroll
    for (int m = 0; m < 2; m++)
#pragma unroll
        for (int kc = 0; kc < 2; kc++) {
            int row = q0 + wid * 32 + m * 16 + lr;
            qf[m][kc] = *reinterpret_cast<const bf16x8*>(
                qbase + (size_t)row * HD_ + kc * 32 + lg * 8);
        }

    bf16x8 ones;
#pragma unroll
    for (int j = 0; j < 8; j++) ones[j] = (__bf16)1.0f;

    f32x4 oacc[2][4] = {};
    f32x4 ssum[2] = {};
    u16* myP = &Pt[wid][0];

    auto STAGE = [&](int buf, int kt) {
#pragma unroll
        for (int p = 0; p < 2; p++) {
            int slot = p * 256 + wid * 64 + lane;
            int row = slot >> 3, sl = slot & 7;
            int slx = sl ^ (row & 7);
            gl16(kbase + (size_t)(kt * 64 + row) * HD_ + slx * 8,
                 &Kb[buf][(p * 256 + wid * 64) * 8]);
            gl16(vbase + (size_t)row * S_ + kt * 64 + slx * 8,
                 &Vb[buf][(p * 256 + wid * 64) * 8]);
        }
    };

    STAGE(0, 0);
    __syncthreads();
    int cur = 0;

    for (int kt = 0; kt < 32; ++kt) {
        if (kt < 31) STAGE(cur ^ 1, kt + 1);

        f32x4 sacc[2][4] = {};
        __builtin_amdgcn_s_setprio(1);
#pragma unroll
        for (int n = 0; n < 4; n++) {
            int row = n * 16 + lr;
#pragma unroll
            for (int kc = 0; kc < 2; kc++) {
                int sl = kc * 4 + lg;
                bf16x8 kb = *reinterpret_cast<const bf16x8*>(
                    &Kb[cur][row * 64 + ((sl ^ (row & 7)) * 8)]);
                sacc[0][n] = mfma16(qf[0][kc], kb, sacc[0][n]);
                sacc[1][n] = mfma16(qf[1][kc], kb, sacc[1][n]);
            }
        }
        __builtin_amdgcn_s_setprio(0);
        // P = exp2(s*log2e/8 - 4log2e), packed-convert, wave-private LDS tile
        char* pbase = reinterpret_cast<char*>(myP);
#pragma unroll
        for (int m = 0; m < 2; m++)
#pragma unroll
            for (int n = 0; n < 4; n++) {
                float pv[4];
#pragma unroll
                for (int r = 0; r < 4; r++) {
                    float tt = __builtin_fmaf(sacc[m][n][r], 0.18033688f,
                                              -5.7707802f);
                    asm("v_exp_f32 %0, %1" : "=v"(pv[r]) : "v"(tt));
                }
                u32 d01, d23;
                asm("v_cvt_pk_bf16_f32 %0, %1, %2"
                    : "=v"(d01) : "v"(pv[0]), "v"(pv[1]));
                asm("v_cvt_pk_bf16_f32 %0, %1, %2"
                    : "=v"(d23) : "v"(pv[2]), "v"(pv[3]));
                const int pr = m * 16 + lg * 4;
                const int cb = (n * 16 + lr) * 2;
                *reinterpret_cast<u16*>(pbase + (pr + 0) * 128 +
                                        (cb ^ (((pr + 0) & 7) << 4))) = (u16)d01;
                *reinterpret_cast<u16*>(pbase + (pr + 1) * 128 +
                                        (cb ^ (((pr + 1) & 7) << 4))) = (u16)(d01 >> 16);
                *reinterpret_cast<u16*>(pbase + (pr + 2) * 128 +
                                        (cb ^ (((pr + 2) & 7) << 4))) = (u16)d23;
                *reinterpret_cast<u16*>(pbase + (pr + 3) * 128 +
                                        (cb ^ (((pr + 3) & 7) << 4))) = (u16)(d23 >> 16);
            }
        // PV + row-sum (wave-private P: same-wave DS ordering suffices)
        bf16x8 pa[2][2];
#pragma unroll
        for (int m = 0; m < 2; m++)
#pragma unroll
            for (int kc = 0; kc < 2; kc++) {
                int row = m * 16 + lr;
                int sl = kc * 4 + lg;
                pa[m][kc] = *reinterpret_cast<const bf16x8*>(
                    &myP[row * 64 + ((sl ^ (row & 7)) * 8)]);
            }
        __builtin_amdgcn_s_setprio(1);
#pragma unroll
        for (int n = 0; n < 4; n++) {
            int row = n * 16 + lr;  // row of V tile = d index
#pragma unroll
            for (int kc = 0; kc < 2; kc++) {
                int sl = kc * 4 + lg;
                bf16x8 vb = *reinterpret_cast<const bf16x8*>(
                    &Vb[cur][row * 64 + ((sl ^ (row & 7)) * 8)]);
                oacc[0][n] = mfma16(pa[0][kc], vb, oacc[0][n]);
                oacc[1][n] = mfma16(pa[1][kc], vb, oacc[1][n]);
            }
        }
        ssum[0] = mfma16(pa[0][0], ones, ssum[0]);
        ssum[0] = mfma16(pa[0][1], ones, ssum[0]);
        ssum[1] = mfma16(pa[1][0], ones, ssum[1]);
        ssum[1] = mfma16(pa[1][1], ones, ssum[1]);
        __builtin_amdgcn_s_setprio(0);

        __syncthreads();
        cur ^= 1;
    }

    // epilogue: divide, write bf16 [B,S,D]
    const int b = bh >> 4, h = bh & 15;
#pragma unroll
    for (int m = 0; m < 2; m++)
#pragma unroll
        for (int n = 0; n < 4; n++)
#pragma unroll
            for (int r = 0; r < 4; r++) {
                int q = q0 + wid * 32 + m * 16 + lg * 4 + r;
                int d = n * 16 + lr;
                float v = oacc[m][n][r] / ssum[m][r];
                oag[(size_t)(b * S_ + q) * D_ + h * 64 + d] = f2bf(v);
            }
}

// ---------------------------------------------------------------------------
extern "C" void kernel_launch(void* const* d_in, const int* in_sizes, int n_in,
                              void* d_out, int out_size, void* d_ws, size_t ws_size,
                              hipStream_t stream) {
    (void)in_sizes; (void)n_in; (void)out_size; (void)ws_size;
    const float* x  = (const float*)d_in[0];
    const float* qw = (const float*)d_in[1];
    const float* qb = (const float*)d_in[2];
    const float* kw = (const float*)d_in[3];
    const float* kb = (const float*)d_in[4];
    const float* vw = (const float*)d_in[5];
    const float* vb = (const float*)d_in[6];
    const float* ow = (const float*)d_in[7];
    const float* ob = (const float*)d_in[8];

    u16* ws = (u16*)d_ws;
    const size_t C = 4194304;  // 4096*1024 elements
    u16* xbf = ws + 0 * C;
    u16* wt  = ws + 1 * C;  // 4 transposed bf16 weights [out][in] (q,k,v,o)
    u16* qag = ws + 2 * C;
    u16* kag = ws + 3 * C;
    u16* vtg = ws + 4 * C;
    u16* oag = ws + 5 * C;

    convert_x_kernel<<<4096, 256, 0, stream>>>(x, xbf, (int)(C / 4));
    trans_w_kernel<<<dim3(32, 32, 4), dim3(32, 8), 0, stream>>>(
        qw, kw, vw, ow, wt);

    // fused QKV projection: A=[4096][1024] x B^T=[3072][1024], LIF epilogue
    qkv_gemm<<<dim3(24, 32), 256, 0, stream>>>(
        xbf, wt, qb, kb, vb, qag, kag, vtg);
    attn_kernel<<<dim3(16, 32), 256, 0, stream>>>(qag, kag, vtg, oag);
    // o-projection: plain bf16, tile 64x64 -> 1024 blocks = 4/CU
    o_gemm<<<dim3(16, 64), 256, 0, stream>>>(
        oag, wt + 3 * 1048576, ob, (float*)d_out);
}